// Round 1
// baseline (1059.095 us; speedup 1.0000x reference)
//
#include <hip/hip_runtime.h>
#include <math.h>

#define SZ 48
#define NC 2304          // SIZE*SIZE
#define BB 4
#define DD 32
#define NH 4
#define HD 8
#define NL 2
#define DFF 2048
#define KS 4             // attention k-splits
#define QT 64            // queries per attention block

// ws layout in floats
#define OFF_TABLE 16
#define OFF_X   256
#define OFF_Q   (OFF_X + BB*NC*DD)
#define OFF_K   (OFF_Q + BB*NH*NC*HD)
#define OFF_V   (OFF_K + BB*NH*NC*HD)
#define OFF_O   (OFF_V + BB*NH*NC*HD)
#define OFF_P   (OFF_O + BB*NC*DD)
// P: BB*NH * NC * KS * 9  = 1,327,104 floats; total ws use ~11.2 MB

__device__ __forceinline__ float gelu_exact(float x) {
    return 0.5f * x * (1.0f + erff(x * 0.7071067811865476f));
}

// ---------------------------------------------------------------- setup
// one block, 512 threads: agent argmax, 4 hypo positions, 8-combo MLP table
__global__ void setup_kernel(const float* __restrict__ obs,
    const float* __restrict__ w1, const float* __restrict__ b1,
    const float* __restrict__ w2, const float* __restrict__ b2,
    const float* __restrict__ w3, const float* __restrict__ b3,
    const float* __restrict__ w4, const float* __restrict__ b4,
    float* __restrict__ ws)
{
    __shared__ int s_agent;
    __shared__ float h1[8][64];
    __shared__ float h2[8][128];
    __shared__ float h3[8][64];
    int tid = threadIdx.x;
    if (tid == 0) s_agent = 0;
    __syncthreads();
    for (int n = tid; n < NC; n += 512)
        if (obs[n] > 0.5f) atomicMax(&s_agent, n);
    __syncthreads();
    int a = s_agent;
    if (tid < 4) {
        const int di[4] = {-1, 1, 0, 0};
        const int dj[4] = {0, 0, -1, 1};
        int ai = a / SZ, aj = a % SZ;
        int ni = ai + di[tid], nj = aj + dj[tid];
        bool inb = (ni >= 0) && (ni < SZ) && (nj >= 0) && (nj < SZ);
        int nic = min(max(ni, 0), SZ - 1), njc = min(max(nj, 0), SZ - 1);
        bool ok = inb && (obs[2 * NC + nic * SZ + njc] == 0.0f);
        int ti = ok ? nic : ai, tj = ok ? njc : aj;
        ((int*)ws)[tid] = ti * SZ + tj;
    }
    // layer 1: 8 combos x 64
    {
        int c = tid >> 6, j = tid & 63;
        float in0 = (float)((c >> 2) & 1);
        float in1 = (float)((c >> 1) & 1);
        float in2 = (float)(c & 1);
        float v = b1[j] + w1[j*3+0]*in0 + w1[j*3+1]*in1 + w1[j*3+2]*in2;
        h1[c][j] = gelu_exact(v);
    }
    __syncthreads();
    // layer 2: 8 x 128 (two passes of 512)
    for (int it = 0; it < 2; ++it) {
        int idx = tid + it * 512;
        int c = idx >> 7, j = idx & 127;
        float v = b2[j];
        for (int k = 0; k < 64; ++k) v += w2[j*64+k] * h1[c][k];
        h2[c][j] = gelu_exact(v);
    }
    __syncthreads();
    // layer 3: 8 x 64
    {
        int c = tid >> 6, j = tid & 63;
        float v = b3[j];
        for (int k = 0; k < 128; ++k) v += w3[j*128+k] * h2[c][k];
        h3[c][j] = gelu_exact(v);
    }
    __syncthreads();
    // layer 4: 8 x 16, no gelu
    if (tid < 128) {
        int c = tid >> 4, j = tid & 15;
        float v = b4[j];
        for (int k = 0; k < 64; ++k) v += w4[j*64+k] * h3[c][k];
        ws[OFF_TABLE + c*16 + j] = v;
    }
}

// ---------------------------------------------------------------- tokens
// thread per (b,n): build 32-dim token
__global__ void tokens_kernel(const float* __restrict__ obs,
    const float* __restrict__ abs_emb,
    const float* __restrict__ rel_w, const float* __restrict__ rel_b,
    const float* __restrict__ ang_w, const float* __restrict__ ang_b,
    const float* __restrict__ nbr_w, const float* __restrict__ nbr_b,
    float* __restrict__ ws)
{
    __shared__ float tab[128];
    __shared__ int apos[4];
    int tid = threadIdx.x;
    if (tid < 128) tab[tid] = ws[OFF_TABLE + tid];
    if (tid < 4) apos[tid] = ((const int*)ws)[tid];
    __syncthreads();
    int gid = blockIdx.x * 256 + tid;
    int b = gid / NC, n = gid % NC;
    int ap = apos[b];
    const float* goal = obs + NC;
    const float* wall = obs + 2 * NC;

    int i = n / SZ, j = n % SZ;
    int c0 = ((n == ap) ? 4 : 0) | ((goal[n] > 0.5f) ? 2 : 0) | ((wall[n] > 0.5f) ? 1 : 0);
    int nb[4];
    nb[0] = (i > 0)      ? n - SZ : n;
    nb[1] = (i < SZ - 1) ? n + SZ : n;
    nb[2] = (j > 0)      ? n - 1  : n;
    nb[3] = (j < SZ - 1) ? n + 1  : n;
    float navg[16];
    #pragma unroll
    for (int c = 0; c < 16; ++c) navg[c] = 0.f;
    #pragma unroll
    for (int q = 0; q < 4; ++q) {
        int m = nb[q];
        int cq = ((m == ap) ? 4 : 0) | ((goal[m] > 0.5f) ? 2 : 0) | ((wall[m] > 0.5f) ? 1 : 0);
        #pragma unroll
        for (int c = 0; c < 16; ++c) navg[c] += tab[cq*16 + c];
    }
    float* xrow = ws + OFF_X + (size_t)gid * DD;
    #pragma unroll
    for (int c = 0; c < 16; ++c) xrow[c] = tab[c0*16 + c];
    #pragma unroll
    for (int o = 0; o < 4; ++o) xrow[16 + o] = abs_emb[n*4 + o];
    int ar = ap / SZ, ac = ap % SZ;
    const float scc = 2.0f / (SZ - 1);
    float dr = (float)(ar - i) * scc;
    float dc = (float)(ac - j) * scc;
    #pragma unroll
    for (int o = 0; o < 4; ++o) xrow[20 + o] = rel_b[o] + rel_w[o*2+0]*dr + rel_w[o*2+1]*dc;
    float ang = atan2f(dc, dr);
    float sa = sinf(ang), ca = cosf(ang);
    #pragma unroll
    for (int o = 0; o < 4; ++o) xrow[24 + o] = ang_b[o] + ang_w[o*2+0]*sa + ang_w[o*2+1]*ca;
    #pragma unroll
    for (int o = 0; o < 4; ++o) {
        float v = nbr_b[o];
        #pragma unroll
        for (int c = 0; c < 16; ++c) v += nbr_w[o*16 + c] * (navg[c] * 0.25f);
        xrow[28 + o] = v;
    }
}

// ---------------------------------------------------------------- qkv
// thread per (token, out-dim o<96); W staged transposed+padded in LDS
__global__ void qkv_kernel(const float* __restrict__ X,
    const float* __restrict__ W, const float* __restrict__ bias,
    float* __restrict__ Q, float* __restrict__ K, float* __restrict__ V)
{
    __shared__ float Ws[DD * 97];   // Ws[d*97 + o]
    __shared__ float Bs[96];
    int tid = threadIdx.x;
    for (int idx = tid; idx < 96 * DD; idx += 256) {
        int o = idx / DD, d = idx % DD;
        Ws[d*97 + o] = W[idx];
    }
    if (tid < 96) Bs[tid] = bias[tid];
    __syncthreads();
    int gid = blockIdx.x * 256 + tid;
    int t = gid / 96, o = gid % 96;
    const float* xr = X + (size_t)t * DD;
    float s = Bs[o];
    #pragma unroll
    for (int d = 0; d < DD; ++d) s += Ws[d*97 + o] * xr[d];
    int b = t / NC, n = t % NC;
    int part = o >> 5;
    int oo = o & 31;
    int h = oo >> 3, dd = oo & 7;
    float* dst = (part == 0) ? Q : (part == 1) ? K : V;
    dst[(((size_t)(b * NH + h)) * NC + n) * HD + dd] = s;
}

// ---------------------------------------------------------------- attention partial
// block = 1 wave (64 queries), covers one k-split (576 keys). No max-sub
// (scores bounded tiny) -> partials combine exactly by summation.
__global__ void attn_partial(const float* __restrict__ Q,
    const float* __restrict__ K, const float* __restrict__ V,
    float* __restrict__ P)
{
    __shared__ __align__(16) float Kt[QT][HD];
    __shared__ __align__(16) float Vt[QT][HD];
    int bi = blockIdx.x;                 // 16*36*4
    int ks = bi & 3;
    int qt = (bi >> 2) % 36;
    int bh = bi / (36 * 4);
    int lane = threadIdx.x;
    int q = qt * QT + lane;
    const float* qp = Q + ((size_t)bh * NC + q) * HD;
    float qr[HD];
    #pragma unroll
    for (int d = 0; d < HD; ++d) qr[d] = qp[d] * 0.35355339059327373f; // 1/sqrt(8)
    float acc[HD] = {0, 0, 0, 0, 0, 0, 0, 0};
    float lsum = 0.f;
    int k0 = ks * (NC / KS);
    for (int tile = 0; tile < (NC / KS) / QT; ++tile) {
        int kbase = k0 + tile * QT;
        const float4* kp = (const float4*)(K + ((size_t)bh * NC + kbase + lane) * HD);
        const float4* vp = (const float4*)(V + ((size_t)bh * NC + kbase + lane) * HD);
        __syncthreads();
        ((float4*)Kt[lane])[0] = kp[0];
        ((float4*)Kt[lane])[1] = kp[1];
        ((float4*)Vt[lane])[0] = vp[0];
        ((float4*)Vt[lane])[1] = vp[1];
        __syncthreads();
        #pragma unroll 4
        for (int kk = 0; kk < QT; ++kk) {
            float s = 0.f;
            #pragma unroll
            for (int d = 0; d < HD; ++d) s += qr[d] * Kt[kk][d];
            float p = __expf(s);
            lsum += p;
            #pragma unroll
            for (int d = 0; d < HD; ++d) acc[d] += p * Vt[kk][d];
        }
    }
    float* pp = P + (((size_t)bh * NC + q) * KS + ks) * 9;
    #pragma unroll
    for (int d = 0; d < HD; ++d) pp[d] = acc[d];
    pp[8] = lsum;
}

// ---------------------------------------------------------------- attention combine
__global__ void attn_combine(const float* __restrict__ P, float* __restrict__ O)
{
    int gid = blockIdx.x * 256 + threadIdx.x;   // 16*2304
    int bh = gid / NC, q = gid % NC;
    float acc[HD] = {0, 0, 0, 0, 0, 0, 0, 0};
    float lsum = 0.f;
    for (int s = 0; s < KS; ++s) {
        const float* pp = P + (((size_t)bh * NC + q) * KS + s) * 9;
        #pragma unroll
        for (int d = 0; d < HD; ++d) acc[d] += pp[d];
        lsum += pp[8];
    }
    float inv = 1.0f / lsum;
    int b = bh / NH, h = bh % NH;
    float* op = O + ((size_t)(b * NC + q)) * DD + h * HD;
    #pragma unroll
    for (int d = 0; d < HD; ++d) op[d] = acc[d] * inv;
}

// ---------------------------------------------------------------- out-proj + residual + LN1
__global__ void proj_ln1(float* __restrict__ X, const float* __restrict__ O,
    const float* __restrict__ W, const float* __restrict__ bias,
    const float* __restrict__ g, const float* __restrict__ bbp)
{
    int gid = blockIdx.x * 256 + threadIdx.x;   // token
    float orow[DD], y[DD];
    const float* op = O + (size_t)gid * DD;
    float* xp = X + (size_t)gid * DD;
    #pragma unroll
    for (int d = 0; d < DD; ++d) orow[d] = op[d];
    float mu = 0.f;
    #pragma unroll
    for (int o = 0; o < DD; ++o) {
        float s = bias[o];
        #pragma unroll
        for (int d = 0; d < DD; ++d) s += W[o*DD + d] * orow[d];
        y[o] = xp[o] + s;
        mu += y[o];
    }
    mu *= (1.0f / DD);
    float var = 0.f;
    #pragma unroll
    for (int o = 0; o < DD; ++o) { float t = y[o] - mu; var += t * t; }
    var *= (1.0f / DD);
    float inv = 1.0f / sqrtf(var + 1e-5f);
    #pragma unroll
    for (int o = 0; o < DD; ++o) xp[o] = (y[o] - mu) * inv * g[o] + bbp[o];
}

// ---------------------------------------------------------------- fused FF + residual + LN2
// block: 256 threads, 16 tokens; h tile (16x256) lives in LDS, never HBM
#define FT 16
#define FC 256
__global__ void ff_kernel(float* __restrict__ X,
    const float* __restrict__ w1, const float* __restrict__ b1,
    const float* __restrict__ w2, const float* __restrict__ b2,
    const float* __restrict__ g, const float* __restrict__ bbp)
{
    __shared__ float Xs[FT * DD];
    __shared__ float H[FT * 257];    // padded stride
    __shared__ float OUT[FT * 33];   // padded stride
    int tid = threadIdx.x;
    int t0 = blockIdx.x * FT;
    for (int i = tid; i < FT * DD; i += 256)
        Xs[i] = X[(size_t)t0 * DD + i];
    __syncthreads();
    float acc0 = 0.f, acc1 = 0.f;
    int tt = tid >> 4;
    int dp = tid & 15;
    int d0 = dp * 2, d1 = d0 + 1;
    for (int c = 0; c < DFF; c += FC) {
        int f = c + tid;
        float w1r[DD];
        #pragma unroll
        for (int d = 0; d < DD; ++d) w1r[d] = w1[(size_t)f * DD + d];
        float bf = b1[f];
        #pragma unroll
        for (int t = 0; t < FT; ++t) {
            float s = bf;
            #pragma unroll
            for (int d = 0; d < DD; ++d) s += w1r[d] * Xs[t*DD + d];
            H[t*257 + tid] = fmaxf(s, 0.f);
        }
        __syncthreads();
        const float* w2r0 = w2 + (size_t)d0 * DFF + c;
        const float* w2r1 = w2 + (size_t)d1 * DFF + c;
        #pragma unroll 4
        for (int fc = 0; fc < FC; ++fc) {
            float h = H[tt*257 + fc];
            acc0 += h * w2r0[fc];
            acc1 += h * w2r1[fc];
        }
        __syncthreads();
    }
    OUT[tt*33 + d0] = acc0;
    OUT[tt*33 + d1] = acc1;
    __syncthreads();
    if (tid < FT) {
        int t = tid;
        float y[DD];
        float mu = 0.f;
        #pragma unroll
        for (int d = 0; d < DD; ++d) {
            y[d] = Xs[t*DD + d] + OUT[t*33 + d] + b2[d];
            mu += y[d];
        }
        mu *= (1.0f / DD);
        float var = 0.f;
        #pragma unroll
        for (int d = 0; d < DD; ++d) { float z = y[d] - mu; var += z * z; }
        var *= (1.0f / DD);
        float inv = 1.0f / sqrtf(var + 1e-5f);
        float* xp = X + (size_t)(t0 + t) * DD;
        #pragma unroll
        for (int d = 0; d < DD; ++d) xp[d] = (y[d] - mu) * inv * g[d] + bbp[d];
    }
}

// ---------------------------------------------------------------- final mean over tokens
__global__ void mean_kernel(const float* __restrict__ X, float* __restrict__ out)
{
    __shared__ float sp[8][DD];
    int b = blockIdx.x;
    int tid = threadIdx.x;
    int d = tid & 31, gix = tid >> 5;
    float s = 0.f;
    for (int n = gix; n < NC; n += 8)
        s += X[((size_t)b * NC + n) * DD + d];
    sp[gix][d] = s;
    __syncthreads();
    if (tid < DD) {
        float t = 0.f;
        #pragma unroll
        for (int gg = 0; gg < 8; ++gg) t += sp[gg][d];
        out[b*DD + d] = t * (1.0f / NC);
    }
}

// ---------------------------------------------------------------- launch
extern "C" void kernel_launch(void* const* d_in, const int* in_sizes, int n_in,
                              void* d_out, int out_size, void* d_ws, size_t ws_size,
                              hipStream_t stream) {
    const float* obs       = (const float*)d_in[0];
    const float* mlp_w1    = (const float*)d_in[1];
    const float* mlp_b1    = (const float*)d_in[2];
    const float* mlp_w2    = (const float*)d_in[3];
    const float* mlp_b2    = (const float*)d_in[4];
    const float* mlp_w3    = (const float*)d_in[5];
    const float* mlp_b3    = (const float*)d_in[6];
    const float* mlp_w4    = (const float*)d_in[7];
    const float* mlp_b4    = (const float*)d_in[8];
    const float* abs_emb   = (const float*)d_in[9];
    const float* rel_w     = (const float*)d_in[10];
    const float* rel_b     = (const float*)d_in[11];
    const float* ang_w     = (const float*)d_in[12];
    const float* ang_b     = (const float*)d_in[13];
    const float* nbr_w     = (const float*)d_in[14];
    const float* nbr_b     = (const float*)d_in[15];
    const float* attn_in_w = (const float*)d_in[16];
    const float* attn_in_b = (const float*)d_in[17];
    const float* attn_out_w= (const float*)d_in[18];
    const float* attn_out_b= (const float*)d_in[19];
    const float* ff_w1     = (const float*)d_in[20];
    const float* ff_b1     = (const float*)d_in[21];
    const float* ff_w2     = (const float*)d_in[22];
    const float* ff_b2     = (const float*)d_in[23];
    const float* ln1_g     = (const float*)d_in[24];
    const float* ln1_b     = (const float*)d_in[25];
    const float* ln2_g     = (const float*)d_in[26];
    const float* ln2_b     = (const float*)d_in[27];

    float* ws = (float*)d_ws;
    float* X = ws + OFF_X;
    float* Q = ws + OFF_Q;
    float* K = ws + OFF_K;
    float* V = ws + OFF_V;
    float* O = ws + OFF_O;
    float* P = ws + OFF_P;

    setup_kernel<<<1, 512, 0, stream>>>(obs, mlp_w1, mlp_b1, mlp_w2, mlp_b2,
                                        mlp_w3, mlp_b3, mlp_w4, mlp_b4, ws);
    tokens_kernel<<<36, 256, 0, stream>>>(obs, abs_emb, rel_w, rel_b,
                                          ang_w, ang_b, nbr_w, nbr_b, ws);
    for (int l = 0; l < NL; ++l) {
        qkv_kernel<<<(BB*NC*96)/256, 256, 0, stream>>>(
            X, attn_in_w + (size_t)l*96*DD, attn_in_b + (size_t)l*96, Q, K, V);
        attn_partial<<<BB*NH*36*KS, 64, 0, stream>>>(Q, K, V, P);
        attn_combine<<<(BB*NH*NC)/256, 256, 0, stream>>>(P, O);
        proj_ln1<<<(BB*NC)/256, 256, 0, stream>>>(
            X, O, attn_out_w + (size_t)l*DD*DD, attn_out_b + (size_t)l*DD,
            ln1_g + (size_t)l*DD, ln1_b + (size_t)l*DD);
        ff_kernel<<<(BB*NC)/FT, 256, 0, stream>>>(
            X, ff_w1 + (size_t)l*DFF*DD, ff_b1 + (size_t)l*DFF,
            ff_w2 + (size_t)l*DD*DFF, ff_b2 + (size_t)l*DD,
            ln2_g + (size_t)l*DD, ln2_b + (size_t)l*DD);
    }
    mean_kernel<<<BB, 256, 0, stream>>>(X, (float*)d_out);
}

// Round 2
// 407.775 us; speedup vs baseline: 2.5973x; 2.5973x over previous
//
#include <hip/hip_runtime.h>
#include <hip/hip_bf16.h>
#include <math.h>

#define SZ 48
#define NC 2304          // SIZE*SIZE
#define BB 4
#define DD 32
#define NH 4
#define HD 8
#define NL 2
#define DFF 2048
#define KS 4             // attention k-splits
#define QT 64            // queries per attention block

// ws layout in floats
#define OFF_TABLE 16
#define OFF_X   256
#define OFF_Q   (OFF_X + BB*NC*DD)
#define OFF_K   (OFF_Q + BB*NH*NC*HD)
#define OFF_V   (OFF_K + BB*NH*NC*HD)
#define OFF_O   (OFF_V + BB*NH*NC*HD)
#define OFF_P   (OFF_O + BB*NC*DD)
#define P_FLOATS (BB*NH*NC*KS*9)
// bf16 X aliases P's region (disjoint lifetimes: P used in attn, Xbf in ff)
#define OFF_XBF OFF_P
// bf16 weights after P (persist across layers)
#define OFF_W1B (OFF_P + P_FLOATS)
#define OFF_W2B (OFF_W1B + (NL*DFF*DD)/2)

typedef __bf16 bf16x8 __attribute__((ext_vector_type(8)));
typedef float f32x4 __attribute__((ext_vector_type(4)));

__device__ __forceinline__ float gelu_exact(float x) {
    return 0.5f * x * (1.0f + erff(x * 0.7071067811865476f));
}

// ---------------------------------------------------------------- setup
__global__ void setup_kernel(const float* __restrict__ obs,
    const float* __restrict__ w1, const float* __restrict__ b1,
    const float* __restrict__ w2, const float* __restrict__ b2,
    const float* __restrict__ w3, const float* __restrict__ b3,
    const float* __restrict__ w4, const float* __restrict__ b4,
    float* __restrict__ ws)
{
    __shared__ int s_agent;
    __shared__ float h1[8][64];
    __shared__ float h2[8][128];
    __shared__ float h3[8][64];
    int tid = threadIdx.x;
    if (tid == 0) s_agent = 0;
    __syncthreads();
    for (int n = tid; n < NC; n += 512)
        if (obs[n] > 0.5f) atomicMax(&s_agent, n);
    __syncthreads();
    int a = s_agent;
    if (tid < 4) {
        const int di[4] = {-1, 1, 0, 0};
        const int dj[4] = {0, 0, -1, 1};
        int ai = a / SZ, aj = a % SZ;
        int ni = ai + di[tid], nj = aj + dj[tid];
        bool inb = (ni >= 0) && (ni < SZ) && (nj >= 0) && (nj < SZ);
        int nic = min(max(ni, 0), SZ - 1), njc = min(max(nj, 0), SZ - 1);
        bool ok = inb && (obs[2 * NC + nic * SZ + njc] == 0.0f);
        int ti = ok ? nic : ai, tj = ok ? njc : aj;
        ((int*)ws)[tid] = ti * SZ + tj;
    }
    {
        int c = tid >> 6, j = tid & 63;
        float in0 = (float)((c >> 2) & 1);
        float in1 = (float)((c >> 1) & 1);
        float in2 = (float)(c & 1);
        float v = b1[j] + w1[j*3+0]*in0 + w1[j*3+1]*in1 + w1[j*3+2]*in2;
        h1[c][j] = gelu_exact(v);
    }
    __syncthreads();
    for (int it = 0; it < 2; ++it) {
        int idx = tid + it * 512;
        int c = idx >> 7, j = idx & 127;
        float v = b2[j];
        for (int k = 0; k < 64; ++k) v += w2[j*64+k] * h1[c][k];
        h2[c][j] = gelu_exact(v);
    }
    __syncthreads();
    {
        int c = tid >> 6, j = tid & 63;
        float v = b3[j];
        for (int k = 0; k < 128; ++k) v += w3[j*128+k] * h2[c][k];
        h3[c][j] = gelu_exact(v);
    }
    __syncthreads();
    if (tid < 128) {
        int c = tid >> 4, j = tid & 15;
        float v = b4[j];
        for (int k = 0; k < 64; ++k) v += w4[j*64+k] * h3[c][k];
        ws[OFF_TABLE + c*16 + j] = v;
    }
}

// ---------------------------------------------------------------- weights -> bf16
__global__ void convert_weights(const float* __restrict__ w1,
                                const float* __restrict__ w2,
                                __bf16* __restrict__ w1b, __bf16* __restrict__ w2b)
{
    int i = blockIdx.x * 256 + threadIdx.x;   // NL*DFF*DD = 131072
    w1b[i] = (__bf16)w1[i];
    w2b[i] = (__bf16)w2[i];
}

// ---------------------------------------------------------------- tokens
__global__ void tokens_kernel(const float* __restrict__ obs,
    const float* __restrict__ abs_emb,
    const float* __restrict__ rel_w, const float* __restrict__ rel_b,
    const float* __restrict__ ang_w, const float* __restrict__ ang_b,
    const float* __restrict__ nbr_w, const float* __restrict__ nbr_b,
    float* __restrict__ ws)
{
    __shared__ float tab[128];
    __shared__ int apos[4];
    int tid = threadIdx.x;
    if (tid < 128) tab[tid] = ws[OFF_TABLE + tid];
    if (tid < 4) apos[tid] = ((const int*)ws)[tid];
    __syncthreads();
    int gid = blockIdx.x * 256 + tid;
    int b = gid / NC, n = gid % NC;
    int ap = apos[b];
    const float* goal = obs + NC;
    const float* wall = obs + 2 * NC;

    int i = n / SZ, j = n % SZ;
    int c0 = ((n == ap) ? 4 : 0) | ((goal[n] > 0.5f) ? 2 : 0) | ((wall[n] > 0.5f) ? 1 : 0);
    int nb[4];
    nb[0] = (i > 0)      ? n - SZ : n;
    nb[1] = (i < SZ - 1) ? n + SZ : n;
    nb[2] = (j > 0)      ? n - 1  : n;
    nb[3] = (j < SZ - 1) ? n + 1  : n;
    float navg[16];
    #pragma unroll
    for (int c = 0; c < 16; ++c) navg[c] = 0.f;
    #pragma unroll
    for (int q = 0; q < 4; ++q) {
        int m = nb[q];
        int cq = ((m == ap) ? 4 : 0) | ((goal[m] > 0.5f) ? 2 : 0) | ((wall[m] > 0.5f) ? 1 : 0);
        #pragma unroll
        for (int c = 0; c < 16; ++c) navg[c] += tab[cq*16 + c];
    }
    float* xrow = ws + OFF_X + (size_t)gid * DD;
    #pragma unroll
    for (int c = 0; c < 16; ++c) xrow[c] = tab[c0*16 + c];
    #pragma unroll
    for (int o = 0; o < 4; ++o) xrow[16 + o] = abs_emb[n*4 + o];
    int ar = ap / SZ, ac = ap % SZ;
    const float scc = 2.0f / (SZ - 1);
    float dr = (float)(ar - i) * scc;
    float dc = (float)(ac - j) * scc;
    #pragma unroll
    for (int o = 0; o < 4; ++o) xrow[20 + o] = rel_b[o] + rel_w[o*2+0]*dr + rel_w[o*2+1]*dc;
    float ang = atan2f(dc, dr);
    float sa = sinf(ang), ca = cosf(ang);
    #pragma unroll
    for (int o = 0; o < 4; ++o) xrow[24 + o] = ang_b[o] + ang_w[o*2+0]*sa + ang_w[o*2+1]*ca;
    #pragma unroll
    for (int o = 0; o < 4; ++o) {
        float v = nbr_b[o];
        #pragma unroll
        for (int c = 0; c < 16; ++c) v += nbr_w[o*16 + c] * (navg[c] * 0.25f);
        xrow[28 + o] = v;
    }
}

// ---------------------------------------------------------------- qkv
__global__ void qkv_kernel(const float* __restrict__ X,
    const float* __restrict__ W, const float* __restrict__ bias,
    float* __restrict__ Q, float* __restrict__ K, float* __restrict__ V)
{
    __shared__ float Ws[DD * 97];   // Ws[d*97 + o]
    __shared__ float Bs[96];
    int tid = threadIdx.x;
    for (int idx = tid; idx < 96 * DD; idx += 256) {
        int o = idx / DD, d = idx % DD;
        Ws[d*97 + o] = W[idx];
    }
    if (tid < 96) Bs[tid] = bias[tid];
    __syncthreads();
    int gid = blockIdx.x * 256 + tid;
    int t = gid / 96, o = gid % 96;
    const float* xr = X + (size_t)t * DD;
    float s = Bs[o];
    #pragma unroll
    for (int d = 0; d < DD; ++d) s += Ws[d*97 + o] * xr[d];
    int b = t / NC, n = t % NC;
    int part = o >> 5;
    int oo = o & 31;
    int h = oo >> 3, dd = oo & 7;
    float* dst = (part == 0) ? Q : (part == 1) ? K : V;
    dst[(((size_t)(b * NH + h)) * NC + n) * HD + dd] = s;
}

// ---------------------------------------------------------------- attention partial
__global__ void attn_partial(const float* __restrict__ Q,
    const float* __restrict__ K, const float* __restrict__ V,
    float* __restrict__ P)
{
    __shared__ __align__(16) float Kt[QT][HD];
    __shared__ __align__(16) float Vt[QT][HD];
    int bi = blockIdx.x;                 // 16*36*4
    int ks = bi & 3;
    int qt = (bi >> 2) % 36;
    int bh = bi / (36 * 4);
    int lane = threadIdx.x;
    int q = qt * QT + lane;
    const float* qp = Q + ((size_t)bh * NC + q) * HD;
    float qr[HD];
    #pragma unroll
    for (int d = 0; d < HD; ++d) qr[d] = qp[d] * 0.35355339059327373f; // 1/sqrt(8)
    float acc[HD] = {0, 0, 0, 0, 0, 0, 0, 0};
    float lsum = 0.f;
    int k0 = ks * (NC / KS);
    for (int tile = 0; tile < (NC / KS) / QT; ++tile) {
        int kbase = k0 + tile * QT;
        const float4* kp = (const float4*)(K + ((size_t)bh * NC + kbase + lane) * HD);
        const float4* vp = (const float4*)(V + ((size_t)bh * NC + kbase + lane) * HD);
        __syncthreads();
        ((float4*)Kt[lane])[0] = kp[0];
        ((float4*)Kt[lane])[1] = kp[1];
        ((float4*)Vt[lane])[0] = vp[0];
        ((float4*)Vt[lane])[1] = vp[1];
        __syncthreads();
        #pragma unroll 4
        for (int kk = 0; kk < QT; ++kk) {
            float s = 0.f;
            #pragma unroll
            for (int d = 0; d < HD; ++d) s += qr[d] * Kt[kk][d];
            float p = __expf(s);
            lsum += p;
            #pragma unroll
            for (int d = 0; d < HD; ++d) acc[d] += p * Vt[kk][d];
        }
    }
    float* pp = P + (((size_t)bh * NC + q) * KS + ks) * 9;
    #pragma unroll
    for (int d = 0; d < HD; ++d) pp[d] = acc[d];
    pp[8] = lsum;
}

// ---------------------------------------------------------------- attention combine
__global__ void attn_combine(const float* __restrict__ P, float* __restrict__ O)
{
    int gid = blockIdx.x * 256 + threadIdx.x;   // 16*2304
    int bh = gid / NC, q = gid % NC;
    float acc[HD] = {0, 0, 0, 0, 0, 0, 0, 0};
    float lsum = 0.f;
    for (int s = 0; s < KS; ++s) {
        const float* pp = P + (((size_t)bh * NC + q) * KS + s) * 9;
        #pragma unroll
        for (int d = 0; d < HD; ++d) acc[d] += pp[d];
        lsum += pp[8];
    }
    float inv = 1.0f / lsum;
    int b = bh / NH, h = bh % NH;
    float* op = O + ((size_t)(b * NC + q)) * DD + h * HD;
    #pragma unroll
    for (int d = 0; d < HD; ++d) op[d] = acc[d] * inv;
}

// ---------------------------------------------------------------- out-proj + residual + LN1 (+ bf16 X copy)
__global__ void proj_ln1(float* __restrict__ X, const float* __restrict__ O,
    const float* __restrict__ W, const float* __restrict__ bias,
    const float* __restrict__ g, const float* __restrict__ bbp,
    __bf16* __restrict__ Xb)
{
    int gid = blockIdx.x * 256 + threadIdx.x;   // token
    float orow[DD], y[DD];
    const float* op = O + (size_t)gid * DD;
    float* xp = X + (size_t)gid * DD;
    #pragma unroll
    for (int d = 0; d < DD; ++d) orow[d] = op[d];
    float mu = 0.f;
    #pragma unroll
    for (int o = 0; o < DD; ++o) {
        float s = bias[o];
        #pragma unroll
        for (int d = 0; d < DD; ++d) s += W[o*DD + d] * orow[d];
        y[o] = xp[o] + s;
        mu += y[o];
    }
    mu *= (1.0f / DD);
    float var = 0.f;
    #pragma unroll
    for (int o = 0; o < DD; ++o) { float t = y[o] - mu; var += t * t; }
    var *= (1.0f / DD);
    float inv = 1.0f / sqrtf(var + 1e-5f);
    #pragma unroll
    for (int o = 0; o < DD; ++o) {
        float v = (y[o] - mu) * inv * g[o] + bbp[o];
        xp[o] = v;
        Xb[(size_t)gid * DD + o] = (__bf16)v;
    }
}

// ---------------------------------------------------------------- fused FF via MFMA (bf16 in, fp32 accum)
// 1 wave / 16 tokens; H never touches HBM. Two 32-wide f-chunks in flight.
__global__ void __launch_bounds__(64)
ff_mfma(float* __restrict__ Xf,
        const __bf16* __restrict__ Xb,
        const __bf16* __restrict__ w1b, const float* __restrict__ b1,
        const __bf16* __restrict__ w2b, const float* __restrict__ b2,
        const float* __restrict__ g, const float* __restrict__ bbp)
{
    __shared__ __align__(16) __bf16 Hl[2][648];
    int l = threadIdx.x;
    int lo = l & 15, kg = l >> 4;
    int t0 = blockIdx.x * 16;

    bf16x8 a1 = *reinterpret_cast<const bf16x8*>(Xb + (size_t)(t0 + lo) * DD + kg * 8);
    f32x4 accA0 = {0,0,0,0}, accA1 = {0,0,0,0};
    f32x4 accB0 = {0,0,0,0}, accB1 = {0,0,0,0};
    const f32x4 zero = {0,0,0,0};

    for (int cc = 0; cc < DFF; cc += 64) {
        int cA = cc, cB = cc + 32;
        bf16x8 b1A0 = *reinterpret_cast<const bf16x8*>(w1b + (size_t)(cA + lo) * DD + kg*8);
        bf16x8 b1A1 = *reinterpret_cast<const bf16x8*>(w1b + (size_t)(cA + 16 + lo) * DD + kg*8);
        bf16x8 b1B0 = *reinterpret_cast<const bf16x8*>(w1b + (size_t)(cB + lo) * DD + kg*8);
        bf16x8 b1B1 = *reinterpret_cast<const bf16x8*>(w1b + (size_t)(cB + 16 + lo) * DD + kg*8);
        f32x4 c1A0 = __builtin_amdgcn_mfma_f32_16x16x32_bf16(a1, b1A0, zero, 0, 0, 0);
        f32x4 c1A1 = __builtin_amdgcn_mfma_f32_16x16x32_bf16(a1, b1A1, zero, 0, 0, 0);
        f32x4 c1B0 = __builtin_amdgcn_mfma_f32_16x16x32_bf16(a1, b1B0, zero, 0, 0, 0);
        f32x4 c1B1 = __builtin_amdgcn_mfma_f32_16x16x32_bf16(a1, b1B1, zero, 0, 0, 0);
        float bA0 = b1[cA + lo], bA1 = b1[cA + 16 + lo];
        float bB0 = b1[cB + lo], bB1 = b1[cB + 16 + lo];
        #pragma unroll
        for (int r = 0; r < 4; ++r) {
            int tok = kg * 4 + r;
            Hl[0][tok*40 + lo]      = (__bf16)fmaxf(c1A0[r] + bA0, 0.f);
            Hl[0][tok*40 + 16 + lo] = (__bf16)fmaxf(c1A1[r] + bA1, 0.f);
            Hl[1][tok*40 + lo]      = (__bf16)fmaxf(c1B0[r] + bB0, 0.f);
            Hl[1][tok*40 + 16 + lo] = (__bf16)fmaxf(c1B1[r] + bB1, 0.f);
        }
        bf16x8 a2A = *reinterpret_cast<const bf16x8*>(&Hl[0][lo*40 + kg*8]);
        bf16x8 a2B = *reinterpret_cast<const bf16x8*>(&Hl[1][lo*40 + kg*8]);
        bf16x8 b2A0 = *reinterpret_cast<const bf16x8*>(w2b + (size_t)lo * DFF + cA + kg*8);
        bf16x8 b2A1 = *reinterpret_cast<const bf16x8*>(w2b + (size_t)(16 + lo) * DFF + cA + kg*8);
        bf16x8 b2B0 = *reinterpret_cast<const bf16x8*>(w2b + (size_t)lo * DFF + cB + kg*8);
        bf16x8 b2B1 = *reinterpret_cast<const bf16x8*>(w2b + (size_t)(16 + lo) * DFF + cB + kg*8);
        accA0 = __builtin_amdgcn_mfma_f32_16x16x32_bf16(a2A, b2A0, accA0, 0, 0, 0);
        accA1 = __builtin_amdgcn_mfma_f32_16x16x32_bf16(a2A, b2A1, accA1, 0, 0, 0);
        accB0 = __builtin_amdgcn_mfma_f32_16x16x32_bf16(a2B, b2B0, accB0, 0, 0, 0);
        accB1 = __builtin_amdgcn_mfma_f32_16x16x32_bf16(a2B, b2B1, accB1, 0, 0, 0);
    }

    float b2v0 = b2[lo],      b2v1 = b2[16 + lo];
    float g0   = g[lo],       g1   = g[16 + lo];
    float bb0  = bbp[lo],     bb1  = bbp[16 + lo];
    #pragma unroll
    for (int r = 0; r < 4; ++r) {
        int t = t0 + kg * 4 + r;
        float y0 = Xf[(size_t)t * DD + lo]      + accA0[r] + accB0[r] + b2v0;
        float y1 = Xf[(size_t)t * DD + 16 + lo] + accA1[r] + accB1[r] + b2v1;
        float s = y0 + y1;
        s += __shfl_xor(s, 1, 16); s += __shfl_xor(s, 2, 16);
        s += __shfl_xor(s, 4, 16); s += __shfl_xor(s, 8, 16);
        float mu = s * (1.0f / DD);
        float d0 = y0 - mu, d1 = y1 - mu;
        float v = d0 * d0 + d1 * d1;
        v += __shfl_xor(v, 1, 16); v += __shfl_xor(v, 2, 16);
        v += __shfl_xor(v, 4, 16); v += __shfl_xor(v, 8, 16);
        float inv = 1.0f / sqrtf(v * (1.0f / DD) + 1e-5f);
        Xf[(size_t)t * DD + lo]      = d0 * inv * g0 + bb0;
        Xf[(size_t)t * DD + 16 + lo] = d1 * inv * g1 + bb1;
    }
}

// ---------------------------------------------------------------- final mean over tokens
__global__ void mean_kernel(const float* __restrict__ X, float* __restrict__ out)
{
    __shared__ float sp[8][DD];
    int b = blockIdx.x;
    int tid = threadIdx.x;
    int d = tid & 31, gix = tid >> 5;
    float s = 0.f;
    for (int n = gix; n < NC; n += 8)
        s += X[((size_t)b * NC + n) * DD + d];
    sp[gix][d] = s;
    __syncthreads();
    if (tid < DD) {
        float t = 0.f;
        #pragma unroll
        for (int gg = 0; gg < 8; ++gg) t += sp[gg][d];
        out[b*DD + d] = t * (1.0f / NC);
    }
}

// ---------------------------------------------------------------- launch
extern "C" void kernel_launch(void* const* d_in, const int* in_sizes, int n_in,
                              void* d_out, int out_size, void* d_ws, size_t ws_size,
                              hipStream_t stream) {
    const float* obs       = (const float*)d_in[0];
    const float* mlp_w1    = (const float*)d_in[1];
    const float* mlp_b1    = (const float*)d_in[2];
    const float* mlp_w2    = (const float*)d_in[3];
    const float* mlp_b2    = (const float*)d_in[4];
    const float* mlp_w3    = (const float*)d_in[5];
    const float* mlp_b3    = (const float*)d_in[6];
    const float* mlp_w4    = (const float*)d_in[7];
    const float* mlp_b4    = (const float*)d_in[8];
    const float* abs_emb   = (const float*)d_in[9];
    const float* rel_w     = (const float*)d_in[10];
    const float* rel_b     = (const float*)d_in[11];
    const float* ang_w     = (const float*)d_in[12];
    const float* ang_b     = (const float*)d_in[13];
    const float* nbr_w     = (const float*)d_in[14];
    const float* nbr_b     = (const float*)d_in[15];
    const float* attn_in_w = (const float*)d_in[16];
    const float* attn_in_b = (const float*)d_in[17];
    const float* attn_out_w= (const float*)d_in[18];
    const float* attn_out_b= (const float*)d_in[19];
    const float* ff_w1     = (const float*)d_in[20];
    const float* ff_b1     = (const float*)d_in[21];
    const float* ff_w2     = (const float*)d_in[22];
    const float* ff_b2     = (const float*)d_in[23];
    const float* ln1_g     = (const float*)d_in[24];
    const float* ln1_b     = (const float*)d_in[25];
    const float* ln2_g     = (const float*)d_in[26];
    const float* ln2_b     = (const float*)d_in[27];

    float* ws = (float*)d_ws;
    float* X = ws + OFF_X;
    float* Q = ws + OFF_Q;
    float* K = ws + OFF_K;
    float* V = ws + OFF_V;
    float* O = ws + OFF_O;
    float* P = ws + OFF_P;
    __bf16* Xbf = (__bf16*)(ws + OFF_XBF);
    __bf16* w1b = (__bf16*)(ws + OFF_W1B);
    __bf16* w2b = (__bf16*)(ws + OFF_W2B);

    setup_kernel<<<1, 512, 0, stream>>>(obs, mlp_w1, mlp_b1, mlp_w2, mlp_b2,
                                        mlp_w3, mlp_b3, mlp_w4, mlp_b4, ws);
    convert_weights<<<(NL*DFF*DD)/256, 256, 0, stream>>>(ff_w1, ff_w2, w1b, w2b);
    tokens_kernel<<<36, 256, 0, stream>>>(obs, abs_emb, rel_w, rel_b,
                                          ang_w, ang_b, nbr_w, nbr_b, ws);
    for (int l = 0; l < NL; ++l) {
        qkv_kernel<<<(BB*NC*96)/256, 256, 0, stream>>>(
            X, attn_in_w + (size_t)l*96*DD, attn_in_b + (size_t)l*96, Q, K, V);
        attn_partial<<<BB*NH*36*KS, 64, 0, stream>>>(Q, K, V, P);
        attn_combine<<<(BB*NH*NC)/256, 256, 0, stream>>>(P, O);
        proj_ln1<<<(BB*NC)/256, 256, 0, stream>>>(
            X, O, attn_out_w + (size_t)l*DD*DD, attn_out_b + (size_t)l*DD,
            ln1_g + (size_t)l*DD, ln1_b + (size_t)l*DD, Xbf);
        ff_mfma<<<(BB*NC)/16, 64, 0, stream>>>(
            X, Xbf,
            w1b + (size_t)l*DFF*DD, ff_b1 + (size_t)l*DFF,
            w2b + (size_t)l*DD*DFF, ff_b2 + (size_t)l*DD,
            ln2_g + (size_t)l*DD, ln2_b + (size_t)l*DD);
    }
    mean_kernel<<<BB, 256, 0, stream>>>(X, (float*)d_out);
}

// Round 3
// 250.833 us; speedup vs baseline: 4.2223x; 1.6257x over previous
//
#include <hip/hip_runtime.h>
#include <hip/hip_bf16.h>
#include <math.h>

#define SZ 48
#define NC 2304          // SIZE*SIZE
#define BB 4
#define DD 32
#define NH 4
#define HD 8
#define NL 2
#define DFF 2048
#define KSP 2            // attention k-splits
#define NQB (NC/16)      // 144 query blocks per (b,h)
#define JOBS (BB*NH*NQB*KSP)   // 4608 wave-jobs

// ws layout in floats
#define OFF_TABLE 16
#define OFF_X   256
#define OFF_QB  (OFF_X   + BB*NC*DD)          // bf16 Q (pre-scaled), 294912 halves
#define OFF_KB  (OFF_QB  + (BB*NC*DD)/2)
#define OFF_VT  (OFF_KB  + (BB*NC*DD)/2)      // bf16 V transposed [bh][d][key]
#define OFF_OP  (OFF_VT  + (BB*NC*DD)/2)      // f32 partial O: JOBS*128
#define OFF_RS  (OFF_OP  + JOBS*128)          // f32 partial rsum: JOBS*16
#define OFF_XBF (OFF_RS  + JOBS*16)           // bf16 X copy for ff
#define OFF_W1B (OFF_XBF + (BB*NC*DD)/2)
#define OFF_W2B (OFF_W1B + (NL*DFF*DD)/2)

typedef __bf16 bf16x8 __attribute__((ext_vector_type(8)));
typedef __bf16 bf16x4 __attribute__((ext_vector_type(4)));
typedef float f32x4 __attribute__((ext_vector_type(4)));

__device__ __forceinline__ float gelu_exact(float x) {
    return 0.5f * x * (1.0f + erff(x * 0.7071067811865476f));
}

// ---------------------------------------------------------------- setup
__global__ void setup_kernel(const float* __restrict__ obs,
    const float* __restrict__ w1, const float* __restrict__ b1,
    const float* __restrict__ w2, const float* __restrict__ b2,
    const float* __restrict__ w3, const float* __restrict__ b3,
    const float* __restrict__ w4, const float* __restrict__ b4,
    float* __restrict__ ws)
{
    __shared__ int s_agent;
    __shared__ float h1[8][64];
    __shared__ float h2[8][128];
    __shared__ float h3[8][64];
    int tid = threadIdx.x;
    if (tid == 0) s_agent = 0;
    __syncthreads();
    for (int n = tid; n < NC; n += 512)
        if (obs[n] > 0.5f) atomicMax(&s_agent, n);
    __syncthreads();
    int a = s_agent;
    if (tid < 4) {
        const int di[4] = {-1, 1, 0, 0};
        const int dj[4] = {0, 0, -1, 1};
        int ai = a / SZ, aj = a % SZ;
        int ni = ai + di[tid], nj = aj + dj[tid];
        bool inb = (ni >= 0) && (ni < SZ) && (nj >= 0) && (nj < SZ);
        int nic = min(max(ni, 0), SZ - 1), njc = min(max(nj, 0), SZ - 1);
        bool ok = inb && (obs[2 * NC + nic * SZ + njc] == 0.0f);
        int ti = ok ? nic : ai, tj = ok ? njc : aj;
        ((int*)ws)[tid] = ti * SZ + tj;
    }
    {
        int c = tid >> 6, j = tid & 63;
        float in0 = (float)((c >> 2) & 1);
        float in1 = (float)((c >> 1) & 1);
        float in2 = (float)(c & 1);
        float v = b1[j] + w1[j*3+0]*in0 + w1[j*3+1]*in1 + w1[j*3+2]*in2;
        h1[c][j] = gelu_exact(v);
    }
    __syncthreads();
    for (int it = 0; it < 2; ++it) {
        int idx = tid + it * 512;
        int c = idx >> 7, j = idx & 127;
        float v = b2[j];
        for (int k = 0; k < 64; ++k) v += w2[j*64+k] * h1[c][k];
        h2[c][j] = gelu_exact(v);
    }
    __syncthreads();
    {
        int c = tid >> 6, j = tid & 63;
        float v = b3[j];
        for (int k = 0; k < 128; ++k) v += w3[j*128+k] * h2[c][k];
        h3[c][j] = gelu_exact(v);
    }
    __syncthreads();
    if (tid < 128) {
        int c = tid >> 4, j = tid & 15;
        float v = b4[j];
        for (int k = 0; k < 64; ++k) v += w4[j*64+k] * h3[c][k];
        ws[OFF_TABLE + c*16 + j] = v;
    }
}

// ---------------------------------------------------------------- weights -> bf16
__global__ void convert_weights(const float* __restrict__ w1,
                                const float* __restrict__ w2,
                                __bf16* __restrict__ w1b, __bf16* __restrict__ w2b)
{
    int i = blockIdx.x * 256 + threadIdx.x;   // NL*DFF*DD = 131072
    w1b[i] = (__bf16)w1[i];
    w2b[i] = (__bf16)w2[i];
}

// ---------------------------------------------------------------- tokens
__global__ void tokens_kernel(const float* __restrict__ obs,
    const float* __restrict__ abs_emb,
    const float* __restrict__ rel_w, const float* __restrict__ rel_b,
    const float* __restrict__ ang_w, const float* __restrict__ ang_b,
    const float* __restrict__ nbr_w, const float* __restrict__ nbr_b,
    float* __restrict__ ws)
{
    __shared__ float tab[128];
    __shared__ int apos[4];
    int tid = threadIdx.x;
    if (tid < 128) tab[tid] = ws[OFF_TABLE + tid];
    if (tid < 4) apos[tid] = ((const int*)ws)[tid];
    __syncthreads();
    int gid = blockIdx.x * 256 + tid;
    int b = gid / NC, n = gid % NC;
    int ap = apos[b];
    const float* goal = obs + NC;
    const float* wall = obs + 2 * NC;

    int i = n / SZ, j = n % SZ;
    int c0 = ((n == ap) ? 4 : 0) | ((goal[n] > 0.5f) ? 2 : 0) | ((wall[n] > 0.5f) ? 1 : 0);
    int nb[4];
    nb[0] = (i > 0)      ? n - SZ : n;
    nb[1] = (i < SZ - 1) ? n + SZ : n;
    nb[2] = (j > 0)      ? n - 1  : n;
    nb[3] = (j < SZ - 1) ? n + 1  : n;
    float navg[16];
    #pragma unroll
    for (int c = 0; c < 16; ++c) navg[c] = 0.f;
    #pragma unroll
    for (int q = 0; q < 4; ++q) {
        int m = nb[q];
        int cq = ((m == ap) ? 4 : 0) | ((goal[m] > 0.5f) ? 2 : 0) | ((wall[m] > 0.5f) ? 1 : 0);
        #pragma unroll
        for (int c = 0; c < 16; ++c) navg[c] += tab[cq*16 + c];
    }
    float* xrow = ws + OFF_X + (size_t)gid * DD;
    #pragma unroll
    for (int c = 0; c < 16; ++c) xrow[c] = tab[c0*16 + c];
    #pragma unroll
    for (int o = 0; o < 4; ++o) xrow[16 + o] = abs_emb[n*4 + o];
    int ar = ap / SZ, ac = ap % SZ;
    const float scc = 2.0f / (SZ - 1);
    float dr = (float)(ar - i) * scc;
    float dc = (float)(ac - j) * scc;
    #pragma unroll
    for (int o = 0; o < 4; ++o) xrow[20 + o] = rel_b[o] + rel_w[o*2+0]*dr + rel_w[o*2+1]*dc;
    float ang = atan2f(dc, dr);
    float sa = sinf(ang), ca = cosf(ang);
    #pragma unroll
    for (int o = 0; o < 4; ++o) xrow[24 + o] = ang_b[o] + ang_w[o*2+0]*sa + ang_w[o*2+1]*ca;
    #pragma unroll
    for (int o = 0; o < 4; ++o) {
        float v = nbr_b[o];
        #pragma unroll
        for (int c = 0; c < 16; ++c) v += nbr_w[o*16 + c] * (navg[c] * 0.25f);
        xrow[28 + o] = v;
    }
}

// ---------------------------------------------------------------- qkv (bf16 out; Q pre-scaled; V transposed)
__global__ void qkv_kernel(const float* __restrict__ X,
    const float* __restrict__ W, const float* __restrict__ bias,
    __bf16* __restrict__ Qb, __bf16* __restrict__ Kb, __bf16* __restrict__ Vt)
{
    __shared__ float Ws[DD * 97];   // Ws[d*97 + o]
    __shared__ float Bs[96];
    int tid = threadIdx.x;
    for (int idx = tid; idx < 96 * DD; idx += 256) {
        int o = idx / DD, d = idx % DD;
        Ws[d*97 + o] = W[idx];
    }
    if (tid < 96) Bs[tid] = bias[tid];
    __syncthreads();
    int gid = blockIdx.x * 256 + tid;
    int t = gid / 96, o = gid % 96;
    const float* xr = X + (size_t)t * DD;
    float s = Bs[o];
    #pragma unroll
    for (int d = 0; d < DD; ++d) s += Ws[d*97 + o] * xr[d];
    int b = t / NC, n = t % NC;
    int part = o >> 5;
    int oo = o & 31;
    int h = oo >> 3, dd = oo & 7;
    size_t bh = (size_t)(b * NH + h);
    if (part == 0)
        Qb[(bh * NC + n) * HD + dd] = (__bf16)(s * 0.35355339059327373f);
    else if (part == 1)
        Kb[(bh * NC + n) * HD + dd] = (__bf16)s;
    else
        Vt[(bh * HD + dd) * NC + n] = (__bf16)s;
}

// ---------------------------------------------------------------- attention via MFMA
// wave = one (bh, 16-query block, k-half). S computed transposed (A=K, B=Q)
// so each lane's 4 exp'd P values are contiguous keys -> one ds_write_b64.
// PV: A = P (LDS bounce), B = Vt columns; V col 8 = ones => acc col 8 = rsum.
// No barriers: P-tile is wave-private, DS pipe is in-order per wave.
__global__ void __launch_bounds__(256)
attn_mfma(const __bf16* __restrict__ Qb, const __bf16* __restrict__ Kb,
          const __bf16* __restrict__ Vt, float* __restrict__ Op,
          float* __restrict__ Rs)
{
    __shared__ __bf16 Pl[4][16 * 36];   // per-wave 16q x 32k, row stride 36
    int tid = threadIdx.x;
    int w = tid >> 6, l = tid & 63, lo = l & 15, kg = l >> 4;
    int job = blockIdx.x * 4 + w;
    int bh  = job / (NQB * KSP);
    int rem = job % (NQB * KSP);
    int qb = rem >> 1, ks = rem & 1;

    const f32x4 zero = {0, 0, 0, 0};
    bf16x8 qfrag = {};
    if (kg == 0)
        qfrag = *reinterpret_cast<const bf16x8*>(Qb + ((size_t)bh * NC + qb * 16 + lo) * HD);
    f32x4 acc = zero;
    __bf16* pl = &Pl[w][0];

    for (int ch = 0; ch < (NC / KSP) / 32; ++ch) {   // 36 chunks of 32 keys
        int k0 = ks * (NC / KSP) + ch * 32;
        bf16x8 kf0 = {}, kf1 = {};
        if (kg == 0) {
            kf0 = *reinterpret_cast<const bf16x8*>(Kb + ((size_t)bh * NC + k0 + lo) * HD);
            kf1 = *reinterpret_cast<const bf16x8*>(Kb + ((size_t)bh * NC + k0 + 16 + lo) * HD);
        }
        // S^T tiles: rows = keys, cols = queries
        f32x4 s0 = __builtin_amdgcn_mfma_f32_16x16x32_bf16(kf0, qfrag, zero, 0, 0, 0);
        f32x4 s1 = __builtin_amdgcn_mfma_f32_16x16x32_bf16(kf1, qfrag, zero, 0, 0, 0);
        bf16x4 p0, p1;
        #pragma unroll
        for (int r = 0; r < 4; ++r) p0[r] = (__bf16)__expf(s0[r]);
        #pragma unroll
        for (int r = 0; r < 4; ++r) p1[r] = (__bf16)__expf(s1[r]);
        // P[q=lo][key kg*4+r (+16)] -> packed 8B writes
        *reinterpret_cast<bf16x4*>(pl + lo * 36 + kg * 4)      = p0;
        *reinterpret_cast<bf16x4*>(pl + lo * 36 + 16 + kg * 4) = p1;
        // A2 frag: P[row=lo][kslot kg*8..+7]
        bf16x8 pa = *reinterpret_cast<const bf16x8*>(pl + lo * 36 + kg * 8);
        bf16x8 vf = {};
        if (lo < 8) {
            vf = *reinterpret_cast<const bf16x8*>(Vt + ((size_t)bh * HD + lo) * NC + k0 + kg * 8);
        } else if (lo == 8) {
            #pragma unroll
            for (int j = 0; j < 8; ++j) vf[j] = (__bf16)1.0f;
        }
        acc = __builtin_amdgcn_mfma_f32_16x16x32_bf16(pa, vf, acc, 0, 0, 0);
    }
    // acc: row = q local (kg*4+r), col = lo (d<8: O partial; d==8: rsum)
    if (lo < 8) {
        #pragma unroll
        for (int r = 0; r < 4; ++r)
            Op[(size_t)job * 128 + (kg * 4 + r) * 8 + lo] = acc[r];
    } else if (lo == 8) {
        #pragma unroll
        for (int r = 0; r < 4; ++r)
            Rs[(size_t)job * 16 + kg * 4 + r] = acc[r];
    }
}

// ---------------------------------------------------------------- combine + out-proj + residual + LN1 (+ bf16 X copy)
__global__ void proj_ln1(float* __restrict__ X,
    const float* __restrict__ Op, const float* __restrict__ Rs,
    const float* __restrict__ W, const float* __restrict__ bias,
    const float* __restrict__ g, const float* __restrict__ bbp,
    __bf16* __restrict__ Xb)
{
    int gid = blockIdx.x * 256 + threadIdx.x;   // token
    int b = gid / NC, n = gid % NC;
    int qb = n >> 4, qi = n & 15;
    float orow[DD], y[DD];
    #pragma unroll
    for (int h = 0; h < NH; ++h) {
        int jb = ((b * NH + h) * NQB + qb) * KSP;
        float rs = Rs[jb * 16 + qi] + Rs[(jb + 1) * 16 + qi];
        float inv = 1.0f / rs;
        #pragma unroll
        for (int d = 0; d < 8; ++d) {
            float o = Op[(size_t)jb * 128 + qi * 8 + d]
                    + Op[(size_t)(jb + 1) * 128 + qi * 8 + d];
            orow[h * 8 + d] = o * inv;
        }
    }
    float* xp = X + (size_t)gid * DD;
    float mu = 0.f;
    #pragma unroll
    for (int o = 0; o < DD; ++o) {
        float s = bias[o];
        #pragma unroll
        for (int d = 0; d < DD; ++d) s += W[o*DD + d] * orow[d];
        y[o] = xp[o] + s;
        mu += y[o];
    }
    mu *= (1.0f / DD);
    float var = 0.f;
    #pragma unroll
    for (int o = 0; o < DD; ++o) { float t = y[o] - mu; var += t * t; }
    var *= (1.0f / DD);
    float inv = 1.0f / sqrtf(var + 1e-5f);
    #pragma unroll
    for (int o = 0; o < DD; ++o) {
        float v = (y[o] - mu) * inv * g[o] + bbp[o];
        xp[o] = v;
        Xb[(size_t)gid * DD + o] = (__bf16)v;
    }
}

// ---------------------------------------------------------------- fused FF via MFMA (bf16 in, fp32 accum)
__global__ void __launch_bounds__(64)
ff_mfma(float* __restrict__ Xf,
        const __bf16* __restrict__ Xb,
        const __bf16* __restrict__ w1b, const float* __restrict__ b1,
        const __bf16* __restrict__ w2b, const float* __restrict__ b2,
        const float* __restrict__ g, const float* __restrict__ bbp)
{
    __shared__ __align__(16) __bf16 Hl[2][648];
    int l = threadIdx.x;
    int lo = l & 15, kg = l >> 4;
    int t0 = blockIdx.x * 16;

    bf16x8 a1 = *reinterpret_cast<const bf16x8*>(Xb + (size_t)(t0 + lo) * DD + kg * 8);
    f32x4 accA0 = {0,0,0,0}, accA1 = {0,0,0,0};
    f32x4 accB0 = {0,0,0,0}, accB1 = {0,0,0,0};
    const f32x4 zero = {0,0,0,0};

    for (int cc = 0; cc < DFF; cc += 64) {
        int cA = cc, cB = cc + 32;
        bf16x8 b1A0 = *reinterpret_cast<const bf16x8*>(w1b + (size_t)(cA + lo) * DD + kg*8);
        bf16x8 b1A1 = *reinterpret_cast<const bf16x8*>(w1b + (size_t)(cA + 16 + lo) * DD + kg*8);
        bf16x8 b1B0 = *reinterpret_cast<const bf16x8*>(w1b + (size_t)(cB + lo) * DD + kg*8);
        bf16x8 b1B1 = *reinterpret_cast<const bf16x8*>(w1b + (size_t)(cB + 16 + lo) * DD + kg*8);
        f32x4 c1A0 = __builtin_amdgcn_mfma_f32_16x16x32_bf16(a1, b1A0, zero, 0, 0, 0);
        f32x4 c1A1 = __builtin_amdgcn_mfma_f32_16x16x32_bf16(a1, b1A1, zero, 0, 0, 0);
        f32x4 c1B0 = __builtin_amdgcn_mfma_f32_16x16x32_bf16(a1, b1B0, zero, 0, 0, 0);
        f32x4 c1B1 = __builtin_amdgcn_mfma_f32_16x16x32_bf16(a1, b1B1, zero, 0, 0, 0);
        float bA0 = b1[cA + lo], bA1 = b1[cA + 16 + lo];
        float bB0 = b1[cB + lo], bB1 = b1[cB + 16 + lo];
        #pragma unroll
        for (int r = 0; r < 4; ++r) {
            int tok = kg * 4 + r;
            Hl[0][tok*40 + lo]      = (__bf16)fmaxf(c1A0[r] + bA0, 0.f);
            Hl[0][tok*40 + 16 + lo] = (__bf16)fmaxf(c1A1[r] + bA1, 0.f);
            Hl[1][tok*40 + lo]      = (__bf16)fmaxf(c1B0[r] + bB0, 0.f);
            Hl[1][tok*40 + 16 + lo] = (__bf16)fmaxf(c1B1[r] + bB1, 0.f);
        }
        bf16x8 a2A = *reinterpret_cast<const bf16x8*>(&Hl[0][lo*40 + kg*8]);
        bf16x8 a2B = *reinterpret_cast<const bf16x8*>(&Hl[1][lo*40 + kg*8]);
        bf16x8 b2A0 = *reinterpret_cast<const bf16x8*>(w2b + (size_t)lo * DFF + cA + kg*8);
        bf16x8 b2A1 = *reinterpret_cast<const bf16x8*>(w2b + (size_t)(16 + lo) * DFF + cA + kg*8);
        bf16x8 b2B0 = *reinterpret_cast<const bf16x8*>(w2b + (size_t)lo * DFF + cB + kg*8);
        bf16x8 b2B1 = *reinterpret_cast<const bf16x8*>(w2b + (size_t)(16 + lo) * DFF + cB + kg*8);
        accA0 = __builtin_amdgcn_mfma_f32_16x16x32_bf16(a2A, b2A0, accA0, 0, 0, 0);
        accA1 = __builtin_amdgcn_mfma_f32_16x16x32_bf16(a2A, b2A1, accA1, 0, 0, 0);
        accB0 = __builtin_amdgcn_mfma_f32_16x16x32_bf16(a2B, b2B0, accB0, 0, 0, 0);
        accB1 = __builtin_amdgcn_mfma_f32_16x16x32_bf16(a2B, b2B1, accB1, 0, 0, 0);
    }

    float b2v0 = b2[lo],      b2v1 = b2[16 + lo];
    float g0   = g[lo],       g1   = g[16 + lo];
    float bb0  = bbp[lo],     bb1  = bbp[16 + lo];
    #pragma unroll
    for (int r = 0; r < 4; ++r) {
        int t = t0 + kg * 4 + r;
        float y0 = Xf[(size_t)t * DD + lo]      + accA0[r] + accB0[r] + b2v0;
        float y1 = Xf[(size_t)t * DD + 16 + lo] + accA1[r] + accB1[r] + b2v1;
        float s = y0 + y1;
        s += __shfl_xor(s, 1, 16); s += __shfl_xor(s, 2, 16);
        s += __shfl_xor(s, 4, 16); s += __shfl_xor(s, 8, 16);
        float mu = s * (1.0f / DD);
        float d0 = y0 - mu, d1 = y1 - mu;
        float v = d0 * d0 + d1 * d1;
        v += __shfl_xor(v, 1, 16); v += __shfl_xor(v, 2, 16);
        v += __shfl_xor(v, 4, 16); v += __shfl_xor(v, 8, 16);
        float inv = 1.0f / sqrtf(v * (1.0f / DD) + 1e-5f);
        Xf[(size_t)t * DD + lo]      = d0 * inv * g0 + bb0;
        Xf[(size_t)t * DD + 16 + lo] = d1 * inv * g1 + bb1;
    }
}

// ---------------------------------------------------------------- final mean over tokens
__global__ void mean_kernel(const float* __restrict__ X, float* __restrict__ out)
{
    __shared__ float sp[8][DD];
    int b = blockIdx.x;
    int tid = threadIdx.x;
    int d = tid & 31, gix = tid >> 5;
    float s = 0.f;
    for (int n = gix; n < NC; n += 8)
        s += X[((size_t)b * NC + n) * DD + d];
    sp[gix][d] = s;
    __syncthreads();
    if (tid < DD) {
        float t = 0.f;
        #pragma unroll
        for (int gg = 0; gg < 8; ++gg) t += sp[gg][d];
        out[b*DD + d] = t * (1.0f / NC);
    }
}

// ---------------------------------------------------------------- launch
extern "C" void kernel_launch(void* const* d_in, const int* in_sizes, int n_in,
                              void* d_out, int out_size, void* d_ws, size_t ws_size,
                              hipStream_t stream) {
    const float* obs       = (const float*)d_in[0];
    const float* mlp_w1    = (const float*)d_in[1];
    const float* mlp_b1    = (const float*)d_in[2];
    const float* mlp_w2    = (const float*)d_in[3];
    const float* mlp_b2    = (const float*)d_in[4];
    const float* mlp_w3    = (const float*)d_in[5];
    const float* mlp_b3    = (const float*)d_in[6];
    const float* mlp_w4    = (const float*)d_in[7];
    const float* mlp_b4    = (const float*)d_in[8];
    const float* abs_emb   = (const float*)d_in[9];
    const float* rel_w     = (const float*)d_in[10];
    const float* rel_b     = (const float*)d_in[11];
    const float* ang_w     = (const float*)d_in[12];
    const float* ang_b     = (const float*)d_in[13];
    const float* nbr_w     = (const float*)d_in[14];
    const float* nbr_b     = (const float*)d_in[15];
    const float* attn_in_w = (const float*)d_in[16];
    const float* attn_in_b = (const float*)d_in[17];
    const float* attn_out_w= (const float*)d_in[18];
    const float* attn_out_b= (const float*)d_in[19];
    const float* ff_w1     = (const float*)d_in[20];
    const float* ff_b1     = (const float*)d_in[21];
    const float* ff_w2     = (const float*)d_in[22];
    const float* ff_b2     = (const float*)d_in[23];
    const float* ln1_g     = (const float*)d_in[24];
    const float* ln1_b     = (const float*)d_in[25];
    const float* ln2_g     = (const float*)d_in[26];
    const float* ln2_b     = (const float*)d_in[27];

    float* ws = (float*)d_ws;
    float* X  = ws + OFF_X;
    __bf16* Qb = (__bf16*)(ws + OFF_QB);
    __bf16* Kb = (__bf16*)(ws + OFF_KB);
    __bf16* Vt = (__bf16*)(ws + OFF_VT);
    float* Op = ws + OFF_OP;
    float* Rs = ws + OFF_RS;
    __bf16* Xbf = (__bf16*)(ws + OFF_XBF);
    __bf16* w1b = (__bf16*)(ws + OFF_W1B);
    __bf16* w2b = (__bf16*)(ws + OFF_W2B);

    setup_kernel<<<1, 512, 0, stream>>>(obs, mlp_w1, mlp_b1, mlp_w2, mlp_b2,
                                        mlp_w3, mlp_b3, mlp_w4, mlp_b4, ws);
    convert_weights<<<(NL*DFF*DD)/256, 256, 0, stream>>>(ff_w1, ff_w2, w1b, w2b);
    tokens_kernel<<<36, 256, 0, stream>>>(obs, abs_emb, rel_w, rel_b,
                                          ang_w, ang_b, nbr_w, nbr_b, ws);
    for (int l = 0; l < NL; ++l) {
        qkv_kernel<<<(BB*NC*96)/256, 256, 0, stream>>>(
            X, attn_in_w + (size_t)l*96*DD, attn_in_b + (size_t)l*96, Qb, Kb, Vt);
        attn_mfma<<<JOBS/4, 256, 0, stream>>>(Qb, Kb, Vt, Op, Rs);
        proj_ln1<<<(BB*NC)/256, 256, 0, stream>>>(
            X, Op, Rs, attn_out_w + (size_t)l*DD*DD, attn_out_b + (size_t)l*DD,
            ln1_g + (size_t)l*DD, ln1_b + (size_t)l*DD, Xbf);
        ff_mfma<<<(BB*NC)/16, 64, 0, stream>>>(
            X, Xbf,
            w1b + (size_t)l*DFF*DD, ff_b1 + (size_t)l*DFF,
            w2b + (size_t)l*DD*DFF, ff_b2 + (size_t)l*DD,
            ln2_g + (size_t)l*DD, ln2_b + (size_t)l*DD);
    }
    mean_kernel<<<BB, 256, 0, stream>>>(X, (float*)d_out);
}

// Round 4
// 193.530 us; speedup vs baseline: 5.4725x; 1.2961x over previous
//
#include <hip/hip_runtime.h>
#include <hip/hip_bf16.h>
#include <math.h>

#define SZ 48
#define NC 2304          // SIZE*SIZE
#define BB 4
#define DD 32
#define NH 4
#define HD 8
#define NL 2
#define DFF 2048
#define KSP 2            // attention k-splits
#define NQB (NC/16)      // 144 query blocks per (b,h)
#define JOBS (BB*NH*NQB*KSP)   // 4608 wave-jobs
#define MB 32            // mean partial blocks per batch

// ws layout in floats
#define OFF_TABLE 16
#define OFF_X   256
#define OFF_QB  (OFF_X   + BB*NC*DD)          // bf16 Q (pre-scaled), 294912 halves
#define OFF_KB  (OFF_QB  + (BB*NC*DD)/2)
#define OFF_VT  (OFF_KB  + (BB*NC*DD)/2)      // bf16 V transposed [bh][d][key]
#define OFF_OP  (OFF_VT  + (BB*NC*DD)/2)      // f32 partial O: JOBS*128 (reused as mean scratch)
#define OFF_RS  (OFF_OP  + JOBS*128)          // f32 partial rsum: JOBS*16
#define OFF_XBF (OFF_RS  + JOBS*16)           // bf16 X copy for ff
#define OFF_W1B (OFF_XBF + (BB*NC*DD)/2)
#define OFF_W2B (OFF_W1B + (NL*DFF*DD)/2)

typedef __bf16 bf16x8 __attribute__((ext_vector_type(8)));
typedef __bf16 bf16x4 __attribute__((ext_vector_type(4)));
typedef float f32x4 __attribute__((ext_vector_type(4)));

__device__ __forceinline__ float gelu_exact(float x) {
    return 0.5f * x * (1.0f + erff(x * 0.7071067811865476f));
}

// ---------------------------------------------------------------- setup
__global__ void setup_kernel(const float* __restrict__ obs,
    const float* __restrict__ w1, const float* __restrict__ b1,
    const float* __restrict__ w2, const float* __restrict__ b2,
    const float* __restrict__ w3, const float* __restrict__ b3,
    const float* __restrict__ w4, const float* __restrict__ b4,
    float* __restrict__ ws)
{
    __shared__ int s_agent;
    __shared__ float h1[8][64];
    __shared__ float h2[8][128];
    __shared__ float h3[8][64];
    int tid = threadIdx.x;
    if (tid == 0) s_agent = 0;
    __syncthreads();
    for (int n = tid; n < NC; n += 512)
        if (obs[n] > 0.5f) atomicMax(&s_agent, n);
    __syncthreads();
    int a = s_agent;
    if (tid < 4) {
        const int di[4] = {-1, 1, 0, 0};
        const int dj[4] = {0, 0, -1, 1};
        int ai = a / SZ, aj = a % SZ;
        int ni = ai + di[tid], nj = aj + dj[tid];
        bool inb = (ni >= 0) && (ni < SZ) && (nj >= 0) && (nj < SZ);
        int nic = min(max(ni, 0), SZ - 1), njc = min(max(nj, 0), SZ - 1);
        bool ok = inb && (obs[2 * NC + nic * SZ + njc] == 0.0f);
        int ti = ok ? nic : ai, tj = ok ? njc : aj;
        ((int*)ws)[tid] = ti * SZ + tj;
    }
    {
        int c = tid >> 6, j = tid & 63;
        float in0 = (float)((c >> 2) & 1);
        float in1 = (float)((c >> 1) & 1);
        float in2 = (float)(c & 1);
        float v = b1[j] + w1[j*3+0]*in0 + w1[j*3+1]*in1 + w1[j*3+2]*in2;
        h1[c][j] = gelu_exact(v);
    }
    __syncthreads();
    for (int it = 0; it < 2; ++it) {
        int idx = tid + it * 512;
        int c = idx >> 7, j = idx & 127;
        float v = b2[j];
        for (int k = 0; k < 64; ++k) v += w2[j*64+k] * h1[c][k];
        h2[c][j] = gelu_exact(v);
    }
    __syncthreads();
    {
        int c = tid >> 6, j = tid & 63;
        float v = b3[j];
        for (int k = 0; k < 128; ++k) v += w3[j*128+k] * h2[c][k];
        h3[c][j] = gelu_exact(v);
    }
    __syncthreads();
    if (tid < 128) {
        int c = tid >> 4, j = tid & 15;
        float v = b4[j];
        for (int k = 0; k < 64; ++k) v += w4[j*64+k] * h3[c][k];
        ws[OFF_TABLE + c*16 + j] = v;
    }
}

// ---------------------------------------------------------------- weights -> bf16
__global__ void convert_weights(const float* __restrict__ w1,
                                const float* __restrict__ w2,
                                __bf16* __restrict__ w1b, __bf16* __restrict__ w2b)
{
    int i = blockIdx.x * 256 + threadIdx.x;   // NL*DFF*DD = 131072
    w1b[i] = (__bf16)w1[i];
    w2b[i] = (__bf16)w2[i];
}

// ---------------------------------------------------------------- tokens
__global__ void tokens_kernel(const float* __restrict__ obs,
    const float* __restrict__ abs_emb,
    const float* __restrict__ rel_w, const float* __restrict__ rel_b,
    const float* __restrict__ ang_w, const float* __restrict__ ang_b,
    const float* __restrict__ nbr_w, const float* __restrict__ nbr_b,
    float* __restrict__ ws)
{
    __shared__ float tab[128];
    __shared__ int apos[4];
    int tid = threadIdx.x;
    if (tid < 128) tab[tid] = ws[OFF_TABLE + tid];
    if (tid < 4) apos[tid] = ((const int*)ws)[tid];
    __syncthreads();
    int gid = blockIdx.x * 256 + tid;
    int b = gid / NC, n = gid % NC;
    int ap = apos[b];
    const float* goal = obs + NC;
    const float* wall = obs + 2 * NC;

    int i = n / SZ, j = n % SZ;
    int c0 = ((n == ap) ? 4 : 0) | ((goal[n] > 0.5f) ? 2 : 0) | ((wall[n] > 0.5f) ? 1 : 0);
    int nb[4];
    nb[0] = (i > 0)      ? n - SZ : n;
    nb[1] = (i < SZ - 1) ? n + SZ : n;
    nb[2] = (j > 0)      ? n - 1  : n;
    nb[3] = (j < SZ - 1) ? n + 1  : n;
    float navg[16];
    #pragma unroll
    for (int c = 0; c < 16; ++c) navg[c] = 0.f;
    #pragma unroll
    for (int q = 0; q < 4; ++q) {
        int m = nb[q];
        int cq = ((m == ap) ? 4 : 0) | ((goal[m] > 0.5f) ? 2 : 0) | ((wall[m] > 0.5f) ? 1 : 0);
        #pragma unroll
        for (int c = 0; c < 16; ++c) navg[c] += tab[cq*16 + c];
    }
    float* xrow = ws + OFF_X + (size_t)gid * DD;
    #pragma unroll
    for (int c = 0; c < 16; ++c) xrow[c] = tab[c0*16 + c];
    #pragma unroll
    for (int o = 0; o < 4; ++o) xrow[16 + o] = abs_emb[n*4 + o];
    int ar = ap / SZ, ac = ap % SZ;
    const float scc = 2.0f / (SZ - 1);
    float dr = (float)(ar - i) * scc;
    float dc = (float)(ac - j) * scc;
    #pragma unroll
    for (int o = 0; o < 4; ++o) xrow[20 + o] = rel_b[o] + rel_w[o*2+0]*dr + rel_w[o*2+1]*dc;
    float ang = atan2f(dc, dr);
    float sa = sinf(ang), ca = cosf(ang);
    #pragma unroll
    for (int o = 0; o < 4; ++o) xrow[24 + o] = ang_b[o] + ang_w[o*2+0]*sa + ang_w[o*2+1]*ca;
    #pragma unroll
    for (int o = 0; o < 4; ++o) {
        float v = nbr_b[o];
        #pragma unroll
        for (int c = 0; c < 16; ++c) v += nbr_w[o*16 + c] * (navg[c] * 0.25f);
        xrow[28 + o] = v;
    }
}

// ---------------------------------------------------------------- qkv (bf16 out; Q pre-scaled; V transposed)
__global__ void qkv_kernel(const float* __restrict__ X,
    const float* __restrict__ W, const float* __restrict__ bias,
    __bf16* __restrict__ Qb, __bf16* __restrict__ Kb, __bf16* __restrict__ Vt)
{
    __shared__ float Ws[DD * 97];   // Ws[d*97 + o]
    __shared__ float Bs[96];
    int tid = threadIdx.x;
    for (int idx = tid; idx < 96 * DD; idx += 256) {
        int o = idx / DD, d = idx % DD;
        Ws[d*97 + o] = W[idx];
    }
    if (tid < 96) Bs[tid] = bias[tid];
    __syncthreads();
    int gid = blockIdx.x * 256 + tid;
    int t = gid / 96, o = gid % 96;
    const float* xr = X + (size_t)t * DD;
    float s = Bs[o];
    #pragma unroll
    for (int d = 0; d < DD; ++d) s += Ws[d*97 + o] * xr[d];
    int b = t / NC, n = t % NC;
    int part = o >> 5;
    int oo = o & 31;
    int h = oo >> 3, dd = oo & 7;
    size_t bh = (size_t)(b * NH + h);
    if (part == 0)
        Qb[(bh * NC + n) * HD + dd] = (__bf16)(s * 0.35355339059327373f);
    else if (part == 1)
        Kb[(bh * NC + n) * HD + dd] = (__bf16)s;
    else
        Vt[(bh * HD + dd) * NC + n] = (__bf16)s;
}

// ---------------------------------------------------------------- attention via MFMA
__global__ void __launch_bounds__(256)
attn_mfma(const __bf16* __restrict__ Qb, const __bf16* __restrict__ Kb,
          const __bf16* __restrict__ Vt, float* __restrict__ Op,
          float* __restrict__ Rs)
{
    __shared__ __bf16 Pl[4][16 * 36];   // per-wave 16q x 32k, row stride 36
    int tid = threadIdx.x;
    int w = tid >> 6, l = tid & 63, lo = l & 15, kg = l >> 4;
    int job = blockIdx.x * 4 + w;
    int bh  = job / (NQB * KSP);
    int rem = job % (NQB * KSP);
    int qb = rem >> 1, ks = rem & 1;

    const f32x4 zero = {0, 0, 0, 0};
    bf16x8 qfrag = {};
    if (kg == 0)
        qfrag = *reinterpret_cast<const bf16x8*>(Qb + ((size_t)bh * NC + qb * 16 + lo) * HD);
    f32x4 acc = zero;
    __bf16* pl = &Pl[w][0];

    for (int ch = 0; ch < (NC / KSP) / 32; ++ch) {   // 36 chunks of 32 keys
        int k0 = ks * (NC / KSP) + ch * 32;
        bf16x8 kf0 = {}, kf1 = {};
        if (kg == 0) {
            kf0 = *reinterpret_cast<const bf16x8*>(Kb + ((size_t)bh * NC + k0 + lo) * HD);
            kf1 = *reinterpret_cast<const bf16x8*>(Kb + ((size_t)bh * NC + k0 + 16 + lo) * HD);
        }
        f32x4 s0 = __builtin_amdgcn_mfma_f32_16x16x32_bf16(kf0, qfrag, zero, 0, 0, 0);
        f32x4 s1 = __builtin_amdgcn_mfma_f32_16x16x32_bf16(kf1, qfrag, zero, 0, 0, 0);
        bf16x4 p0, p1;
        #pragma unroll
        for (int r = 0; r < 4; ++r) p0[r] = (__bf16)__expf(s0[r]);
        #pragma unroll
        for (int r = 0; r < 4; ++r) p1[r] = (__bf16)__expf(s1[r]);
        *reinterpret_cast<bf16x4*>(pl + lo * 36 + kg * 4)      = p0;
        *reinterpret_cast<bf16x4*>(pl + lo * 36 + 16 + kg * 4) = p1;
        bf16x8 pa = *reinterpret_cast<const bf16x8*>(pl + lo * 36 + kg * 8);
        bf16x8 vf = {};
        if (lo < 8) {
            vf = *reinterpret_cast<const bf16x8*>(Vt + ((size_t)bh * HD + lo) * NC + k0 + kg * 8);
        } else if (lo == 8) {
            #pragma unroll
            for (int j = 0; j < 8; ++j) vf[j] = (__bf16)1.0f;
        }
        acc = __builtin_amdgcn_mfma_f32_16x16x32_bf16(pa, vf, acc, 0, 0, 0);
    }
    if (lo < 8) {
        #pragma unroll
        for (int r = 0; r < 4; ++r)
            Op[(size_t)job * 128 + (kg * 4 + r) * 8 + lo] = acc[r];
    } else if (lo == 8) {
        #pragma unroll
        for (int r = 0; r < 4; ++r)
            Rs[(size_t)job * 16 + kg * 4 + r] = acc[r];
    }
}

// ---------------------------------------------------------------- combine + out-proj + residual + LN1 (+ bf16 X copy)
__global__ void proj_ln1(float* __restrict__ X,
    const float* __restrict__ Op, const float* __restrict__ Rs,
    const float* __restrict__ W, const float* __restrict__ bias,
    const float* __restrict__ g, const float* __restrict__ bbp,
    __bf16* __restrict__ Xb)
{
    int gid = blockIdx.x * 256 + threadIdx.x;   // token
    int b = gid / NC, n = gid % NC;
    int qb = n >> 4, qi = n & 15;
    float orow[DD], y[DD];
    #pragma unroll
    for (int h = 0; h < NH; ++h) {
        int jb = ((b * NH + h) * NQB + qb) * KSP;
        float rs = Rs[jb * 16 + qi] + Rs[(jb + 1) * 16 + qi];
        float inv = 1.0f / rs;
        #pragma unroll
        for (int d = 0; d < 8; ++d) {
            float o = Op[(size_t)jb * 128 + qi * 8 + d]
                    + Op[(size_t)(jb + 1) * 128 + qi * 8 + d];
            orow[h * 8 + d] = o * inv;
        }
    }
    float* xp = X + (size_t)gid * DD;
    float mu = 0.f;
    #pragma unroll
    for (int o = 0; o < DD; ++o) {
        float s = bias[o];
        #pragma unroll
        for (int d = 0; d < DD; ++d) s += W[o*DD + d] * orow[d];
        y[o] = xp[o] + s;
        mu += y[o];
    }
    mu *= (1.0f / DD);
    float var = 0.f;
    #pragma unroll
    for (int o = 0; o < DD; ++o) { float t = y[o] - mu; var += t * t; }
    var *= (1.0f / DD);
    float inv = 1.0f / sqrtf(var + 1e-5f);
    #pragma unroll
    for (int o = 0; o < DD; ++o) {
        float v = (y[o] - mu) * inv * g[o] + bbp[o];
        xp[o] = v;
        Xb[(size_t)gid * DD + o] = (__bf16)v;
    }
}

// ---------------------------------------------------------------- fused FF via MFMA (bf16 in, fp32 accum)
__global__ void __launch_bounds__(64)
ff_mfma(float* __restrict__ Xf,
        const __bf16* __restrict__ Xb,
        const __bf16* __restrict__ w1b, const float* __restrict__ b1,
        const __bf16* __restrict__ w2b, const float* __restrict__ b2,
        const float* __restrict__ g, const float* __restrict__ bbp)
{
    __shared__ __align__(16) __bf16 Hl[2][648];
    int l = threadIdx.x;
    int lo = l & 15, kg = l >> 4;
    int t0 = blockIdx.x * 16;

    bf16x8 a1 = *reinterpret_cast<const bf16x8*>(Xb + (size_t)(t0 + lo) * DD + kg * 8);
    f32x4 accA0 = {0,0,0,0}, accA1 = {0,0,0,0};
    f32x4 accB0 = {0,0,0,0}, accB1 = {0,0,0,0};
    const f32x4 zero = {0,0,0,0};

    for (int cc = 0; cc < DFF; cc += 64) {
        int cA = cc, cB = cc + 32;
        bf16x8 b1A0 = *reinterpret_cast<const bf16x8*>(w1b + (size_t)(cA + lo) * DD + kg*8);
        bf16x8 b1A1 = *reinterpret_cast<const bf16x8*>(w1b + (size_t)(cA + 16 + lo) * DD + kg*8);
        bf16x8 b1B0 = *reinterpret_cast<const bf16x8*>(w1b + (size_t)(cB + lo) * DD + kg*8);
        bf16x8 b1B1 = *reinterpret_cast<const bf16x8*>(w1b + (size_t)(cB + 16 + lo) * DD + kg*8);
        f32x4 c1A0 = __builtin_amdgcn_mfma_f32_16x16x32_bf16(a1, b1A0, zero, 0, 0, 0);
        f32x4 c1A1 = __builtin_amdgcn_mfma_f32_16x16x32_bf16(a1, b1A1, zero, 0, 0, 0);
        f32x4 c1B0 = __builtin_amdgcn_mfma_f32_16x16x32_bf16(a1, b1B0, zero, 0, 0, 0);
        f32x4 c1B1 = __builtin_amdgcn_mfma_f32_16x16x32_bf16(a1, b1B1, zero, 0, 0, 0);
        float bA0 = b1[cA + lo], bA1 = b1[cA + 16 + lo];
        float bB0 = b1[cB + lo], bB1 = b1[cB + 16 + lo];
        #pragma unroll
        for (int r = 0; r < 4; ++r) {
            int tok = kg * 4 + r;
            Hl[0][tok*40 + lo]      = (__bf16)fmaxf(c1A0[r] + bA0, 0.f);
            Hl[0][tok*40 + 16 + lo] = (__bf16)fmaxf(c1A1[r] + bA1, 0.f);
            Hl[1][tok*40 + lo]      = (__bf16)fmaxf(c1B0[r] + bB0, 0.f);
            Hl[1][tok*40 + 16 + lo] = (__bf16)fmaxf(c1B1[r] + bB1, 0.f);
        }
        bf16x8 a2A = *reinterpret_cast<const bf16x8*>(&Hl[0][lo*40 + kg*8]);
        bf16x8 a2B = *reinterpret_cast<const bf16x8*>(&Hl[1][lo*40 + kg*8]);
        bf16x8 b2A0 = *reinterpret_cast<const bf16x8*>(w2b + (size_t)lo * DFF + cA + kg*8);
        bf16x8 b2A1 = *reinterpret_cast<const bf16x8*>(w2b + (size_t)(16 + lo) * DFF + cA + kg*8);
        bf16x8 b2B0 = *reinterpret_cast<const bf16x8*>(w2b + (size_t)lo * DFF + cB + kg*8);
        bf16x8 b2B1 = *reinterpret_cast<const bf16x8*>(w2b + (size_t)(16 + lo) * DFF + cB + kg*8);
        accA0 = __builtin_amdgcn_mfma_f32_16x16x32_bf16(a2A, b2A0, accA0, 0, 0, 0);
        accA1 = __builtin_amdgcn_mfma_f32_16x16x32_bf16(a2A, b2A1, accA1, 0, 0, 0);
        accB0 = __builtin_amdgcn_mfma_f32_16x16x32_bf16(a2B, b2B0, accB0, 0, 0, 0);
        accB1 = __builtin_amdgcn_mfma_f32_16x16x32_bf16(a2B, b2B1, accB1, 0, 0, 0);
    }

    float b2v0 = b2[lo],      b2v1 = b2[16 + lo];
    float g0   = g[lo],       g1   = g[16 + lo];
    float bb0  = bbp[lo],     bb1  = bbp[16 + lo];
    #pragma unroll
    for (int r = 0; r < 4; ++r) {
        int t = t0 + kg * 4 + r;
        float y0 = Xf[(size_t)t * DD + lo]      + accA0[r] + accB0[r] + b2v0;
        float y1 = Xf[(size_t)t * DD + 16 + lo] + accA1[r] + accB1[r] + b2v1;
        float s = y0 + y1;
        s += __shfl_xor(s, 1, 16); s += __shfl_xor(s, 2, 16);
        s += __shfl_xor(s, 4, 16); s += __shfl_xor(s, 8, 16);
        float mu = s * (1.0f / DD);
        float d0 = y0 - mu, d1 = y1 - mu;
        float v = d0 * d0 + d1 * d1;
        v += __shfl_xor(v, 1, 16); v += __shfl_xor(v, 2, 16);
        v += __shfl_xor(v, 4, 16); v += __shfl_xor(v, 8, 16);
        float inv = 1.0f / sqrtf(v * (1.0f / DD) + 1e-5f);
        Xf[(size_t)t * DD + lo]      = d0 * inv * g0 + bb0;
        Xf[(size_t)t * DD + 16 + lo] = d1 * inv * g1 + bb1;
    }
}

// ---------------------------------------------------------------- final mean: stage 1 (128 blocks)
__global__ void mean_part(const float* __restrict__ X, float* __restrict__ part)
{
    __shared__ float sp[8][DD];
    int blk = blockIdx.x;            // BB*MB
    int b = blk / MB, p = blk % MB;
    int tid = threadIdx.x;
    int d = tid & 31, gix = tid >> 5;
    int n0 = p * (NC / MB);          // 72 tokens per block
    float s = 0.f;
    for (int n = n0 + gix; n < n0 + NC / MB; n += 8)
        s += X[((size_t)b * NC + n) * DD + d];
    sp[gix][d] = s;
    __syncthreads();
    if (tid < DD) {
        float t = 0.f;
        #pragma unroll
        for (int gg = 0; gg < 8; ++gg) t += sp[gg][d];
        part[(size_t)(b * MB + p) * DD + d] = t;
    }
}

// ---------------------------------------------------------------- final mean: stage 2 (1 block)
__global__ void mean_fin(const float* __restrict__ part, float* __restrict__ out)
{
    int tid = threadIdx.x;           // 128
    int b = tid >> 5, d = tid & 31;
    float t = 0.f;
    #pragma unroll
    for (int p = 0; p < MB; ++p) t += part[(size_t)(b * MB + p) * DD + d];
    out[b * DD + d] = t * (1.0f / NC);
}

// ---------------------------------------------------------------- launch
extern "C" void kernel_launch(void* const* d_in, const int* in_sizes, int n_in,
                              void* d_out, int out_size, void* d_ws, size_t ws_size,
                              hipStream_t stream) {
    const float* obs       = (const float*)d_in[0];
    const float* mlp_w1    = (const float*)d_in[1];
    const float* mlp_b1    = (const float*)d_in[2];
    const float* mlp_w2    = (const float*)d_in[3];
    const float* mlp_b2    = (const float*)d_in[4];
    const float* mlp_w3    = (const float*)d_in[5];
    const float* mlp_b3    = (const float*)d_in[6];
    const float* mlp_w4    = (const float*)d_in[7];
    const float* mlp_b4    = (const float*)d_in[8];
    const float* abs_emb   = (const float*)d_in[9];
    const float* rel_w     = (const float*)d_in[10];
    const float* rel_b     = (const float*)d_in[11];
    const float* ang_w     = (const float*)d_in[12];
    const float* ang_b     = (const float*)d_in[13];
    const float* nbr_w     = (const float*)d_in[14];
    const float* nbr_b     = (const float*)d_in[15];
    const float* attn_in_w = (const float*)d_in[16];
    const float* attn_in_b = (const float*)d_in[17];
    const float* attn_out_w= (const float*)d_in[18];
    const float* attn_out_b= (const float*)d_in[19];
    const float* ff_w1     = (const float*)d_in[20];
    const float* ff_b1     = (const float*)d_in[21];
    const float* ff_w2     = (const float*)d_in[22];
    const float* ff_b2     = (const float*)d_in[23];
    const float* ln1_g     = (const float*)d_in[24];
    const float* ln1_b     = (const float*)d_in[25];
    const float* ln2_g     = (const float*)d_in[26];
    const float* ln2_b     = (const float*)d_in[27];

    float* ws = (float*)d_ws;
    float* X  = ws + OFF_X;
    __bf16* Qb = (__bf16*)(ws + OFF_QB);
    __bf16* Kb = (__bf16*)(ws + OFF_KB);
    __bf16* Vt = (__bf16*)(ws + OFF_VT);
    float* Op = ws + OFF_OP;
    float* Rs = ws + OFF_RS;
    __bf16* Xbf = (__bf16*)(ws + OFF_XBF);
    __bf16* w1b = (__bf16*)(ws + OFF_W1B);
    __bf16* w2b = (__bf16*)(ws + OFF_W2B);

    setup_kernel<<<1, 512, 0, stream>>>(obs, mlp_w1, mlp_b1, mlp_w2, mlp_b2,
                                        mlp_w3, mlp_b3, mlp_w4, mlp_b4, ws);
    convert_weights<<<(NL*DFF*DD)/256, 256, 0, stream>>>(ff_w1, ff_w2, w1b, w2b);
    tokens_kernel<<<36, 256, 0, stream>>>(obs, abs_emb, rel_w, rel_b,
                                          ang_w, ang_b, nbr_w, nbr_b, ws);
    for (int l = 0; l < NL; ++l) {
        qkv_kernel<<<(BB*NC*96)/256, 256, 0, stream>>>(
            X, attn_in_w + (size_t)l*96*DD, attn_in_b + (size_t)l*96, Qb, Kb, Vt);
        attn_mfma<<<JOBS/4, 256, 0, stream>>>(Qb, Kb, Vt, Op, Rs);
        proj_ln1<<<(BB*NC)/256, 256, 0, stream>>>(
            X, Op, Rs, attn_out_w + (size_t)l*DD*DD, attn_out_b + (size_t)l*DD,
            ln1_g + (size_t)l*DD, ln1_b + (size_t)l*DD, Xbf);
        ff_mfma<<<(BB*NC)/16, 64, 0, stream>>>(
            X, Xbf,
            w1b + (size_t)l*DFF*DD, ff_b1 + (size_t)l*DFF,
            w2b + (size_t)l*DD*DFF, ff_b2 + (size_t)l*DD,
            ln2_g + (size_t)l*DD, ln2_b + (size_t)l*DD);
    }
    mean_part<<<BB*MB, 256, 0, stream>>>(X, Op);   // reuse Op scratch
    mean_fin<<<1, 128, 0, stream>>>(Op, (float*)d_out);
}

// Round 5
// 163.468 us; speedup vs baseline: 6.4789x; 1.1839x over previous
//
#include <hip/hip_runtime.h>
#include <hip/hip_bf16.h>
#include <math.h>

#define SZ 48
#define NC 2304          // SIZE*SIZE
#define BB 4
#define DD 32
#define NH 4
#define HD 8
#define NL 2
#define DFF 2048
#define KSP 2            // attention k-splits
#define NQB (NC/16)      // 144 query blocks per (b,h)
#define JOBS (BB*NH*NQB*KSP)   // 4608 wave-jobs
#define MB 32            // mean partial blocks per batch

// ws layout in floats
#define OFF_TABLE 16
#define OFF_X   256
#define OFF_QB  (OFF_X   + BB*NC*DD)          // bf16 Q (pre-scaled)
#define OFF_KB  (OFF_QB  + (BB*NC*DD)/2)
#define OFF_VT  (OFF_KB  + (BB*NC*DD)/2)      // bf16 V transposed [bh][d][key]
#define OFF_OP  (OFF_VT  + (BB*NC*DD)/2)      // f32 partial O: JOBS*128 (reused as mean scratch)
#define OFF_RS  (OFF_OP  + JOBS*128)          // f32 partial rsum: JOBS*16
#define OFF_XBF (OFF_RS  + JOBS*16)           // bf16 X copy for qkv/ff
#define OFF_W1B (OFF_XBF + (BB*NC*DD)/2)
#define OFF_W2B (OFF_W1B + (NL*DFF*DD)/2)
#define OFF_WQB (OFF_W2B + (NL*DFF*DD)/2)     // bf16 attn_in_w: NL*96*DD halves
#define OFF_WOB (OFF_WQB + (NL*96*DD)/2)      // bf16 attn_out_w: NL*DD*DD halves

typedef __bf16 bf16x8 __attribute__((ext_vector_type(8)));
typedef __bf16 bf16x4 __attribute__((ext_vector_type(4)));
typedef float f32x4 __attribute__((ext_vector_type(4)));

__device__ __forceinline__ float gelu_exact(float x) {
    return 0.5f * x * (1.0f + erff(x * 0.7071067811865476f));
}

// ---------------------------------------------------------------- setup
__global__ void setup_kernel(const float* __restrict__ obs,
    const float* __restrict__ w1, const float* __restrict__ b1,
    const float* __restrict__ w2, const float* __restrict__ b2,
    const float* __restrict__ w3, const float* __restrict__ b3,
    const float* __restrict__ w4, const float* __restrict__ b4,
    float* __restrict__ ws)
{
    __shared__ int s_agent;
    __shared__ float h1[8][64];
    __shared__ float h2[8][128];
    __shared__ float h3[8][64];
    int tid = threadIdx.x;
    if (tid == 0) s_agent = 0;
    __syncthreads();
    for (int n = tid; n < NC; n += 512)
        if (obs[n] > 0.5f) atomicMax(&s_agent, n);
    __syncthreads();
    int a = s_agent;
    if (tid < 4) {
        const int di[4] = {-1, 1, 0, 0};
        const int dj[4] = {0, 0, -1, 1};
        int ai = a / SZ, aj = a % SZ;
        int ni = ai + di[tid], nj = aj + dj[tid];
        bool inb = (ni >= 0) && (ni < SZ) && (nj >= 0) && (nj < SZ);
        int nic = min(max(ni, 0), SZ - 1), njc = min(max(nj, 0), SZ - 1);
        bool ok = inb && (obs[2 * NC + nic * SZ + njc] == 0.0f);
        int ti = ok ? nic : ai, tj = ok ? njc : aj;
        ((int*)ws)[tid] = ti * SZ + tj;
    }
    {
        int c = tid >> 6, j = tid & 63;
        float in0 = (float)((c >> 2) & 1);
        float in1 = (float)((c >> 1) & 1);
        float in2 = (float)(c & 1);
        float v = b1[j] + w1[j*3+0]*in0 + w1[j*3+1]*in1 + w1[j*3+2]*in2;
        h1[c][j] = gelu_exact(v);
    }
    __syncthreads();
    for (int it = 0; it < 2; ++it) {
        int idx = tid + it * 512;
        int c = idx >> 7, j = idx & 127;
        float v = b2[j];
        for (int k = 0; k < 64; ++k) v += w2[j*64+k] * h1[c][k];
        h2[c][j] = gelu_exact(v);
    }
    __syncthreads();
    {
        int c = tid >> 6, j = tid & 63;
        float v = b3[j];
        for (int k = 0; k < 128; ++k) v += w3[j*128+k] * h2[c][k];
        h3[c][j] = gelu_exact(v);
    }
    __syncthreads();
    if (tid < 128) {
        int c = tid >> 4, j = tid & 15;
        float v = b4[j];
        for (int k = 0; k < 64; ++k) v += w4[j*64+k] * h3[c][k];
        ws[OFF_TABLE + c*16 + j] = v;
    }
}

// ---------------------------------------------------------------- weights -> bf16
__global__ void convert_weights(const float* __restrict__ w1,
                                const float* __restrict__ w2,
                                const float* __restrict__ wq,
                                const float* __restrict__ wo,
                                __bf16* __restrict__ w1b, __bf16* __restrict__ w2b,
                                __bf16* __restrict__ wqb, __bf16* __restrict__ wob)
{
    int i = blockIdx.x * 256 + threadIdx.x;   // NL*DFF*DD = 131072
    w1b[i] = (__bf16)w1[i];
    w2b[i] = (__bf16)w2[i];
    if (i < NL*96*DD) wqb[i] = (__bf16)wq[i];
    if (i < NL*DD*DD) wob[i] = (__bf16)wo[i];
}

// ---------------------------------------------------------------- tokens (emits f32 X + bf16 Xb)
__global__ void tokens_kernel(const float* __restrict__ obs,
    const float* __restrict__ abs_emb,
    const float* __restrict__ rel_w, const float* __restrict__ rel_b,
    const float* __restrict__ ang_w, const float* __restrict__ ang_b,
    const float* __restrict__ nbr_w, const float* __restrict__ nbr_b,
    float* __restrict__ ws, __bf16* __restrict__ Xb)
{
    __shared__ float tab[128];
    __shared__ int apos[4];
    int tid = threadIdx.x;
    if (tid < 128) tab[tid] = ws[OFF_TABLE + tid];
    if (tid < 4) apos[tid] = ((const int*)ws)[tid];
    __syncthreads();
    int gid = blockIdx.x * 256 + tid;
    int b = gid / NC, n = gid % NC;
    int ap = apos[b];
    const float* goal = obs + NC;
    const float* wall = obs + 2 * NC;

    int i = n / SZ, j = n % SZ;
    int c0 = ((n == ap) ? 4 : 0) | ((goal[n] > 0.5f) ? 2 : 0) | ((wall[n] > 0.5f) ? 1 : 0);
    int nb[4];
    nb[0] = (i > 0)      ? n - SZ : n;
    nb[1] = (i < SZ - 1) ? n + SZ : n;
    nb[2] = (j > 0)      ? n - 1  : n;
    nb[3] = (j < SZ - 1) ? n + 1  : n;
    float navg[16];
    #pragma unroll
    for (int c = 0; c < 16; ++c) navg[c] = 0.f;
    #pragma unroll
    for (int q = 0; q < 4; ++q) {
        int m = nb[q];
        int cq = ((m == ap) ? 4 : 0) | ((goal[m] > 0.5f) ? 2 : 0) | ((wall[m] > 0.5f) ? 1 : 0);
        #pragma unroll
        for (int c = 0; c < 16; ++c) navg[c] += tab[cq*16 + c];
    }
    float val[DD];
    #pragma unroll
    for (int c = 0; c < 16; ++c) val[c] = tab[c0*16 + c];
    #pragma unroll
    for (int o = 0; o < 4; ++o) val[16 + o] = abs_emb[n*4 + o];
    int ar = ap / SZ, ac = ap % SZ;
    const float scc = 2.0f / (SZ - 1);
    float dr = (float)(ar - i) * scc;
    float dc = (float)(ac - j) * scc;
    #pragma unroll
    for (int o = 0; o < 4; ++o) val[20 + o] = rel_b[o] + rel_w[o*2+0]*dr + rel_w[o*2+1]*dc;
    float ang = atan2f(dc, dr);
    float sa = sinf(ang), ca = cosf(ang);
    #pragma unroll
    for (int o = 0; o < 4; ++o) val[24 + o] = ang_b[o] + ang_w[o*2+0]*sa + ang_w[o*2+1]*ca;
    #pragma unroll
    for (int o = 0; o < 4; ++o) {
        float v = nbr_b[o];
        #pragma unroll
        for (int c = 0; c < 16; ++c) v += nbr_w[o*16 + c] * (navg[c] * 0.25f);
        val[28 + o] = v;
    }
    float* xrow = ws + OFF_X + (size_t)gid * DD;
    #pragma unroll
    for (int d = 0; d < DD; ++d) {
        xrow[d] = val[d];
        Xb[(size_t)gid * DD + d] = (__bf16)val[d];
    }
}

// ---------------------------------------------------------------- qkv via MFMA
// 1 wave / 16 tokens: A = Xb tile, 6 B-frags from bf16 W; scatter epilogue.
__global__ void __launch_bounds__(64)
qkv_mfma(const __bf16* __restrict__ Xb,
         const __bf16* __restrict__ Wq, const float* __restrict__ bias,
         __bf16* __restrict__ Qb, __bf16* __restrict__ Kb, __bf16* __restrict__ Vt)
{
    int l = threadIdx.x;
    int lo = l & 15, kg = l >> 4;
    int t0 = blockIdx.x * 16;
    const f32x4 zero = {0, 0, 0, 0};

    bf16x8 a = *reinterpret_cast<const bf16x8*>(Xb + (size_t)(t0 + lo) * DD + kg * 8);
    f32x4 acc[6];
    #pragma unroll
    for (int n = 0; n < 6; ++n) {
        bf16x8 bf = *reinterpret_cast<const bf16x8*>(Wq + (size_t)(n * 16 + lo) * DD + kg * 8);
        acc[n] = __builtin_amdgcn_mfma_f32_16x16x32_bf16(a, bf, zero, 0, 0, 0);
    }
    int b = t0 / NC;
    #pragma unroll
    for (int n = 0; n < 6; ++n) {
        int o = n * 16 + lo;
        float bi = bias[o];
        int part = o >> 5, oo = o & 31;
        int h = oo >> 3, dd = oo & 7;
        size_t bh = (size_t)(b * NH + h);
        #pragma unroll
        for (int r = 0; r < 4; ++r) {
            int t = t0 + kg * 4 + r;
            int nn = t % NC;
            float s = acc[n][r] + bi;
            if (part == 0)
                Qb[(bh * NC + nn) * HD + dd] = (__bf16)(s * 0.35355339059327373f);
            else if (part == 1)
                Kb[(bh * NC + nn) * HD + dd] = (__bf16)s;
            else
                Vt[(bh * HD + dd) * NC + nn] = (__bf16)s;
        }
    }
}

// ---------------------------------------------------------------- attention via MFMA
__global__ void __launch_bounds__(256)
attn_mfma(const __bf16* __restrict__ Qb, const __bf16* __restrict__ Kb,
          const __bf16* __restrict__ Vt, float* __restrict__ Op,
          float* __restrict__ Rs)
{
    __shared__ __bf16 Pl[4][16 * 36];   // per-wave 16q x 32k, row stride 36
    int tid = threadIdx.x;
    int w = tid >> 6, l = tid & 63, lo = l & 15, kg = l >> 4;
    int job = blockIdx.x * 4 + w;
    int bh  = job / (NQB * KSP);
    int rem = job % (NQB * KSP);
    int qb = rem >> 1, ks = rem & 1;

    const f32x4 zero = {0, 0, 0, 0};
    bf16x8 qfrag = {};
    if (kg == 0)
        qfrag = *reinterpret_cast<const bf16x8*>(Qb + ((size_t)bh * NC + qb * 16 + lo) * HD);
    f32x4 acc = zero;
    __bf16* pl = &Pl[w][0];

    for (int ch = 0; ch < (NC / KSP) / 32; ++ch) {   // 36 chunks of 32 keys
        int k0 = ks * (NC / KSP) + ch * 32;
        bf16x8 kf0 = {}, kf1 = {};
        if (kg == 0) {
            kf0 = *reinterpret_cast<const bf16x8*>(Kb + ((size_t)bh * NC + k0 + lo) * HD);
            kf1 = *reinterpret_cast<const bf16x8*>(Kb + ((size_t)bh * NC + k0 + 16 + lo) * HD);
        }
        f32x4 s0 = __builtin_amdgcn_mfma_f32_16x16x32_bf16(kf0, qfrag, zero, 0, 0, 0);
        f32x4 s1 = __builtin_amdgcn_mfma_f32_16x16x32_bf16(kf1, qfrag, zero, 0, 0, 0);
        bf16x4 p0, p1;
        #pragma unroll
        for (int r = 0; r < 4; ++r) p0[r] = (__bf16)__expf(s0[r]);
        #pragma unroll
        for (int r = 0; r < 4; ++r) p1[r] = (__bf16)__expf(s1[r]);
        *reinterpret_cast<bf16x4*>(pl + lo * 36 + kg * 4)      = p0;
        *reinterpret_cast<bf16x4*>(pl + lo * 36 + 16 + kg * 4) = p1;
        bf16x8 pa = *reinterpret_cast<const bf16x8*>(pl + lo * 36 + kg * 8);
        bf16x8 vf = {};
        if (lo < 8) {
            vf = *reinterpret_cast<const bf16x8*>(Vt + ((size_t)bh * HD + lo) * NC + k0 + kg * 8);
        } else if (lo == 8) {
            #pragma unroll
            for (int j = 0; j < 8; ++j) vf[j] = (__bf16)1.0f;
        }
        acc = __builtin_amdgcn_mfma_f32_16x16x32_bf16(pa, vf, acc, 0, 0, 0);
    }
    if (lo < 8) {
        #pragma unroll
        for (int r = 0; r < 4; ++r)
            Op[(size_t)job * 128 + (kg * 4 + r) * 8 + lo] = acc[r];
    } else if (lo == 8) {
        #pragma unroll
        for (int r = 0; r < 4; ++r)
            Rs[(size_t)job * 16 + kg * 4 + r] = acc[r];
    }
}

// ---------------------------------------------------------------- combine + out-proj + residual + LN1 via MFMA
// 1 wave / 16 tokens. A-frag built directly from Op/Rs (lane(lo,kg): head kg,
// token lo -> two 32B reads + rsum). 2 MFMAs vs bf16 Wo; ff-style LN epilogue.
__global__ void __launch_bounds__(64)
proj_ln1_mfma(float* __restrict__ Xf,
    const float* __restrict__ Op, const float* __restrict__ Rs,
    const __bf16* __restrict__ Wo, const float* __restrict__ bias,
    const float* __restrict__ g, const float* __restrict__ bbp,
    __bf16* __restrict__ Xb)
{
    int l = threadIdx.x;
    int lo = l & 15, kg = l >> 4;
    int t0 = blockIdx.x * 16;
    int b = t0 / NC, qb = (t0 % NC) >> 4;
    const f32x4 zero = {0, 0, 0, 0};

    // A-frag: orow[t=t0+lo][d=kg*8..+7] = combined head-kg attention output
    int jb = ((b * NH + kg) * NQB + qb) * KSP;
    float rs = Rs[jb * 16 + lo] + Rs[(jb + 1) * 16 + lo];
    float inv = 1.0f / rs;
    const float* p0 = Op + (size_t)jb * 128 + lo * 8;
    const float* p1 = Op + (size_t)(jb + 1) * 128 + lo * 8;
    bf16x8 a;
    #pragma unroll
    for (int j = 0; j < 8; ++j) a[j] = (__bf16)((p0[j] + p1[j]) * inv);

    bf16x8 bf0 = *reinterpret_cast<const bf16x8*>(Wo + (size_t)lo * DD + kg * 8);
    bf16x8 bf1 = *reinterpret_cast<const bf16x8*>(Wo + (size_t)(16 + lo) * DD + kg * 8);
    f32x4 acc0 = __builtin_amdgcn_mfma_f32_16x16x32_bf16(a, bf0, zero, 0, 0, 0);
    f32x4 acc1 = __builtin_amdgcn_mfma_f32_16x16x32_bf16(a, bf1, zero, 0, 0, 0);

    float bi0 = bias[lo], bi1 = bias[16 + lo];
    float g0 = g[lo], g1 = g[16 + lo];
    float bb0 = bbp[lo], bb1 = bbp[16 + lo];
    #pragma unroll
    for (int r = 0; r < 4; ++r) {
        int t = t0 + kg * 4 + r;
        float y0 = Xf[(size_t)t * DD + lo]      + acc0[r] + bi0;
        float y1 = Xf[(size_t)t * DD + 16 + lo] + acc1[r] + bi1;
        float s = y0 + y1;
        s += __shfl_xor(s, 1, 16); s += __shfl_xor(s, 2, 16);
        s += __shfl_xor(s, 4, 16); s += __shfl_xor(s, 8, 16);
        float mu = s * (1.0f / DD);
        float d0 = y0 - mu, d1 = y1 - mu;
        float v = d0 * d0 + d1 * d1;
        v += __shfl_xor(v, 1, 16); v += __shfl_xor(v, 2, 16);
        v += __shfl_xor(v, 4, 16); v += __shfl_xor(v, 8, 16);
        float linv = 1.0f / sqrtf(v * (1.0f / DD) + 1e-5f);
        float o0 = d0 * linv * g0 + bb0;
        float o1 = d1 * linv * g1 + bb1;
        Xf[(size_t)t * DD + lo]      = o0;
        Xf[(size_t)t * DD + 16 + lo] = o1;
        Xb[(size_t)t * DD + lo]      = (__bf16)o0;
        Xb[(size_t)t * DD + 16 + lo] = (__bf16)o1;
    }
}

// ---------------------------------------------------------------- fused FF via MFMA (bf16 in, fp32 accum)
__global__ void __launch_bounds__(64)
ff_mfma(float* __restrict__ Xf,
        const __bf16* __restrict__ Xb,
        const __bf16* __restrict__ w1b, const float* __restrict__ b1,
        const __bf16* __restrict__ w2b, const float* __restrict__ b2,
        const float* __restrict__ g, const float* __restrict__ bbp,
        __bf16* __restrict__ XbOut)
{
    __shared__ __align__(16) __bf16 Hl[2][648];
    int l = threadIdx.x;
    int lo = l & 15, kg = l >> 4;
    int t0 = blockIdx.x * 16;

    bf16x8 a1 = *reinterpret_cast<const bf16x8*>(Xb + (size_t)(t0 + lo) * DD + kg * 8);
    f32x4 accA0 = {0,0,0,0}, accA1 = {0,0,0,0};
    f32x4 accB0 = {0,0,0,0}, accB1 = {0,0,0,0};
    const f32x4 zero = {0,0,0,0};

    for (int cc = 0; cc < DFF; cc += 64) {
        int cA = cc, cB = cc + 32;
        bf16x8 b1A0 = *reinterpret_cast<const bf16x8*>(w1b + (size_t)(cA + lo) * DD + kg*8);
        bf16x8 b1A1 = *reinterpret_cast<const bf16x8*>(w1b + (size_t)(cA + 16 + lo) * DD + kg*8);
        bf16x8 b1B0 = *reinterpret_cast<const bf16x8*>(w1b + (size_t)(cB + lo) * DD + kg*8);
        bf16x8 b1B1 = *reinterpret_cast<const bf16x8*>(w1b + (size_t)(cB + 16 + lo) * DD + kg*8);
        f32x4 c1A0 = __builtin_amdgcn_mfma_f32_16x16x32_bf16(a1, b1A0, zero, 0, 0, 0);
        f32x4 c1A1 = __builtin_amdgcn_mfma_f32_16x16x32_bf16(a1, b1A1, zero, 0, 0, 0);
        f32x4 c1B0 = __builtin_amdgcn_mfma_f32_16x16x32_bf16(a1, b1B0, zero, 0, 0, 0);
        f32x4 c1B1 = __builtin_amdgcn_mfma_f32_16x16x32_bf16(a1, b1B1, zero, 0, 0, 0);
        float bA0 = b1[cA + lo], bA1 = b1[cA + 16 + lo];
        float bB0 = b1[cB + lo], bB1 = b1[cB + 16 + lo];
        #pragma unroll
        for (int r = 0; r < 4; ++r) {
            int tok = kg * 4 + r;
            Hl[0][tok*40 + lo]      = (__bf16)fmaxf(c1A0[r] + bA0, 0.f);
            Hl[0][tok*40 + 16 + lo] = (__bf16)fmaxf(c1A1[r] + bA1, 0.f);
            Hl[1][tok*40 + lo]      = (__bf16)fmaxf(c1B0[r] + bB0, 0.f);
            Hl[1][tok*40 + 16 + lo] = (__bf16)fmaxf(c1B1[r] + bB1, 0.f);
        }
        bf16x8 a2A = *reinterpret_cast<const bf16x8*>(&Hl[0][lo*40 + kg*8]);
        bf16x8 a2B = *reinterpret_cast<const bf16x8*>(&Hl[1][lo*40 + kg*8]);
        bf16x8 b2A0 = *reinterpret_cast<const bf16x8*>(w2b + (size_t)lo * DFF + cA + kg*8);
        bf16x8 b2A1 = *reinterpret_cast<const bf16x8*>(w2b + (size_t)(16 + lo) * DFF + cA + kg*8);
        bf16x8 b2B0 = *reinterpret_cast<const bf16x8*>(w2b + (size_t)lo * DFF + cB + kg*8);
        bf16x8 b2B1 = *reinterpret_cast<const bf16x8*>(w2b + (size_t)(16 + lo) * DFF + cB + kg*8);
        accA0 = __builtin_amdgcn_mfma_f32_16x16x32_bf16(a2A, b2A0, accA0, 0, 0, 0);
        accA1 = __builtin_amdgcn_mfma_f32_16x16x32_bf16(a2A, b2A1, accA1, 0, 0, 0);
        accB0 = __builtin_amdgcn_mfma_f32_16x16x32_bf16(a2B, b2B0, accB0, 0, 0, 0);
        accB1 = __builtin_amdgcn_mfma_f32_16x16x32_bf16(a2B, b2B1, accB1, 0, 0, 0);
    }

    float b2v0 = b2[lo],      b2v1 = b2[16 + lo];
    float g0   = g[lo],       g1   = g[16 + lo];
    float bb0  = bbp[lo],     bb1  = bbp[16 + lo];
    #pragma unroll
    for (int r = 0; r < 4; ++r) {
        int t = t0 + kg * 4 + r;
        float y0 = Xf[(size_t)t * DD + lo]      + accA0[r] + accB0[r] + b2v0;
        float y1 = Xf[(size_t)t * DD + 16 + lo] + accA1[r] + accB1[r] + b2v1;
        float s = y0 + y1;
        s += __shfl_xor(s, 1, 16); s += __shfl_xor(s, 2, 16);
        s += __shfl_xor(s, 4, 16); s += __shfl_xor(s, 8, 16);
        float mu = s * (1.0f / DD);
        float d0 = y0 - mu, d1 = y1 - mu;
        float v = d0 * d0 + d1 * d1;
        v += __shfl_xor(v, 1, 16); v += __shfl_xor(v, 2, 16);
        v += __shfl_xor(v, 4, 16); v += __shfl_xor(v, 8, 16);
        float inv = 1.0f / sqrtf(v * (1.0f / DD) + 1e-5f);
        float o0 = d0 * inv * g0 + bb0;
        float o1 = d1 * inv * g1 + bb1;
        Xf[(size_t)t * DD + lo]      = o0;
        Xf[(size_t)t * DD + 16 + lo] = o1;
        XbOut[(size_t)t * DD + lo]      = (__bf16)o0;
        XbOut[(size_t)t * DD + 16 + lo] = (__bf16)o1;
    }
}

// ---------------------------------------------------------------- final mean: stage 1 (128 blocks)
__global__ void mean_part(const float* __restrict__ X, float* __restrict__ part)
{
    __shared__ float sp[8][DD];
    int blk = blockIdx.x;            // BB*MB
    int b = blk / MB, p = blk % MB;
    int tid = threadIdx.x;
    int d = tid & 31, gix = tid >> 5;
    int n0 = p * (NC / MB);          // 72 tokens per block
    float s = 0.f;
    for (int n = n0 + gix; n < n0 + NC / MB; n += 8)
        s += X[((size_t)b * NC + n) * DD + d];
    sp[gix][d] = s;
    __syncthreads();
    if (tid < DD) {
        float t = 0.f;
        #pragma unroll
        for (int gg = 0; gg < 8; ++gg) t += sp[gg][d];
        part[(size_t)(b * MB + p) * DD + d] = t;
    }
}

// ---------------------------------------------------------------- final mean: stage 2 (1 block)
__global__ void mean_fin(const float* __restrict__ part, float* __restrict__ out)
{
    int tid = threadIdx.x;           // 128
    int b = tid >> 5, d = tid & 31;
    float t = 0.f;
    #pragma unroll
    for (int p = 0; p < MB; ++p) t += part[(size_t)(b * MB + p) * DD + d];
    out[b * DD + d] = t * (1.0f / NC);
}

// ---------------------------------------------------------------- launch
extern "C" void kernel_launch(void* const* d_in, const int* in_sizes, int n_in,
                              void* d_out, int out_size, void* d_ws, size_t ws_size,
                              hipStream_t stream) {
    const float* obs       = (const float*)d_in[0];
    const float* mlp_w1    = (const float*)d_in[1];
    const float* mlp_b1    = (const float*)d_in[2];
    const float* mlp_w2    = (const float*)d_in[3];
    const float* mlp_b2    = (const float*)d_in[4];
    const float* mlp_w3    = (const float*)d_in[5];
    const float* mlp_b3    = (const float*)d_in[6];
    const float* mlp_w4    = (const float*)d_in[7];
    const float* mlp_b4    = (const float*)d_in[8];
    const float* abs_emb   = (const float*)d_in[9];
    const float* rel_w     = (const float*)d_in[10];
    const float* rel_b     = (const float*)d_in[11];
    const float* ang_w     = (const float*)d_in[12];
    const float* ang_b     = (const float*)d_in[13];
    const float* nbr_w     = (const float*)d_in[14];
    const float* nbr_b     = (const float*)d_in[15];
    const float* attn_in_w = (const float*)d_in[16];
    const float* attn_in_b = (const float*)d_in[17];
    const float* attn_out_w= (const float*)d_in[18];
    const float* attn_out_b= (const float*)d_in[19];
    const float* ff_w1     = (const float*)d_in[20];
    const float* ff_b1     = (const float*)d_in[21];
    const float* ff_w2     = (const float*)d_in[22];
    const float* ff_b2     = (const float*)d_in[23];
    const float* ln1_g     = (const float*)d_in[24];
    const float* ln1_b     = (const float*)d_in[25];
    const float* ln2_g     = (const float*)d_in[26];
    const float* ln2_b     = (const float*)d_in[27];

    float* ws = (float*)d_ws;
    float* X  = ws + OFF_X;
    __bf16* Qb = (__bf16*)(ws + OFF_QB);
    __bf16* Kb = (__bf16*)(ws + OFF_KB);
    __bf16* Vt = (__bf16*)(ws + OFF_VT);
    float* Op = ws + OFF_OP;
    float* Rs = ws + OFF_RS;
    __bf16* Xbf = (__bf16*)(ws + OFF_XBF);
    __bf16* w1b = (__bf16*)(ws + OFF_W1B);
    __bf16* w2b = (__bf16*)(ws + OFF_W2B);
    __bf16* wqb = (__bf16*)(ws + OFF_WQB);
    __bf16* wob = (__bf16*)(ws + OFF_WOB);

    setup_kernel<<<1, 512, 0, stream>>>(obs, mlp_w1, mlp_b1, mlp_w2, mlp_b2,
                                        mlp_w3, mlp_b3, mlp_w4, mlp_b4, ws);
    convert_weights<<<(NL*DFF*DD)/256, 256, 0, stream>>>(
        ff_w1, ff_w2, attn_in_w, attn_out_w, w1b, w2b, wqb, wob);
    tokens_kernel<<<36, 256, 0, stream>>>(obs, abs_emb, rel_w, rel_b,
                                          ang_w, ang_b, nbr_w, nbr_b, ws, Xbf);
    for (int l = 0; l < NL; ++l) {
        qkv_mfma<<<(BB*NC)/16, 64, 0, stream>>>(
            Xbf, wqb + (size_t)l*96*DD, attn_in_b + (size_t)l*96, Qb, Kb, Vt);
        attn_mfma<<<JOBS/4, 256, 0, stream>>>(Qb, Kb, Vt, Op, Rs);
        proj_ln1_mfma<<<(BB*NC)/16, 64, 0, stream>>>(
            X, Op, Rs, wob + (size_t)l*DD*DD, attn_out_b + (size_t)l*DD,
            ln1_g + (size_t)l*DD, ln1_b + (size_t)l*DD, Xbf);
        ff_mfma<<<(BB*NC)/16, 64, 0, stream>>>(
            X, Xbf,
            w1b + (size_t)l*DFF*DD, ff_b1 + (size_t)l*DFF,
            w2b + (size_t)l*DD*DFF, ff_b2 + (size_t)l*DD,
            ln2_g + (size_t)l*DD, ln2_b + (size_t)l*DD, Xbf);
    }
    mean_part<<<BB*MB, 256, 0, stream>>>(X, Op);   // reuse Op scratch
    mean_fin<<<1, 128, 0, stream>>>(Op, (float*)d_out);
}

// Round 6
// 132.254 us; speedup vs baseline: 8.0080x; 1.2360x over previous
//
#include <hip/hip_runtime.h>
#include <hip/hip_bf16.h>
#include <math.h>

#define SZ 48
#define NC 2304          // SIZE*SIZE
#define BB 4
#define DD 32
#define NH 4
#define HD 8
#define NL 2
#define DFF 2048
#define KSP 2            // attention k-splits
#define NQB (NC/16)      // 144 query blocks per (b,h)
#define JOBS (BB*NH*NQB*KSP)   // 4608 wave-jobs

// ws layout in floats
#define OFF_TABLE 16
#define OFF_X   256
#define OFF_QB  (OFF_X   + BB*NC*DD)          // bf16 Q (pre-scaled)
#define OFF_KB  (OFF_QB  + (BB*NC*DD)/2)
#define OFF_VT  (OFF_KB  + (BB*NC*DD)/2)      // bf16 V transposed [bh][d][key]
#define OFF_OP  (OFF_VT  + (BB*NC*DD)/2)      // f32 partial O: JOBS*128
#define OFF_RS  (OFF_OP  + JOBS*128)          // f32 partial rsum: JOBS*16
#define OFF_W1B (OFF_RS  + JOBS*16)
#define OFF_W2B (OFF_W1B + (NL*DFF*DD)/2)
#define OFF_WQB (OFF_W2B + (NL*DFF*DD)/2)     // bf16 attn_in_w
#define OFF_WOB (OFF_WQB + (NL*96*DD)/2)      // bf16 attn_out_w

typedef __bf16 bf16x8 __attribute__((ext_vector_type(8)));
typedef __bf16 bf16x4 __attribute__((ext_vector_type(4)));
typedef float f32x4 __attribute__((ext_vector_type(4)));

__device__ __forceinline__ float gelu_exact(float x) {
    return 0.5f * x * (1.0f + erff(x * 0.7071067811865476f));
}

// ---------------------------------------------------------------- setup + weight convert + out zero
// block 0: agent/table MLP.  blocks 1..511: bf16 weight conversion.
__global__ void __launch_bounds__(256)
setup_convert(const float* __restrict__ obs,
    const float* __restrict__ w1, const float* __restrict__ b1,
    const float* __restrict__ w2, const float* __restrict__ b2,
    const float* __restrict__ w3, const float* __restrict__ b3,
    const float* __restrict__ w4, const float* __restrict__ b4,
    const float* __restrict__ fw1, const float* __restrict__ fw2,
    const float* __restrict__ wq, const float* __restrict__ wo,
    float* __restrict__ ws,
    __bf16* __restrict__ w1b, __bf16* __restrict__ w2b,
    __bf16* __restrict__ wqb, __bf16* __restrict__ wob,
    float* __restrict__ out)
{
    int blk = blockIdx.x, tid = threadIdx.x;
    if (blk == 1 && tid < BB * DD) out[tid] = 0.f;   // zero accumulator for fused mean
    if (blk > 0) {
        for (int i = (blk - 1) * 256 + tid; i < NL*DFF*DD; i += 511 * 256) {
            w1b[i] = (__bf16)fw1[i];
            w2b[i] = (__bf16)fw2[i];
            if (i < NL*96*DD) wqb[i] = (__bf16)wq[i];
            if (i < NL*DD*DD) wob[i] = (__bf16)wo[i];
        }
        return;
    }
    __shared__ int s_agent;
    __shared__ float h1[8][64];
    __shared__ float h2[8][128];
    __shared__ float h3[8][64];
    if (tid == 0) s_agent = 0;
    __syncthreads();
    for (int n = tid; n < NC; n += 256)
        if (obs[n] > 0.5f) atomicMax(&s_agent, n);
    __syncthreads();
    int a = s_agent;
    if (tid < 4) {
        const int di[4] = {-1, 1, 0, 0};
        const int dj[4] = {0, 0, -1, 1};
        int ai = a / SZ, aj = a % SZ;
        int ni = ai + di[tid], nj = aj + dj[tid];
        bool inb = (ni >= 0) && (ni < SZ) && (nj >= 0) && (nj < SZ);
        int nic = min(max(ni, 0), SZ - 1), njc = min(max(nj, 0), SZ - 1);
        bool ok = inb && (obs[2 * NC + nic * SZ + njc] == 0.0f);
        int ti = ok ? nic : ai, tj = ok ? njc : aj;
        ((int*)ws)[tid] = ti * SZ + tj;
    }
    for (int it = 0; it < 2; ++it) {
        int idx = tid + it * 256;
        int c = idx >> 6, j = idx & 63;
        float in0 = (float)((c >> 2) & 1);
        float in1 = (float)((c >> 1) & 1);
        float in2 = (float)(c & 1);
        float v = b1[j] + w1[j*3+0]*in0 + w1[j*3+1]*in1 + w1[j*3+2]*in2;
        h1[c][j] = gelu_exact(v);
    }
    __syncthreads();
    for (int it = 0; it < 4; ++it) {
        int idx = tid + it * 256;
        int c = idx >> 7, j = idx & 127;
        float v = b2[j];
        for (int k = 0; k < 64; ++k) v += w2[j*64+k] * h1[c][k];
        h2[c][j] = gelu_exact(v);
    }
    __syncthreads();
    for (int it = 0; it < 2; ++it) {
        int idx = tid + it * 256;
        int c = idx >> 6, j = idx & 63;
        float v = b3[j];
        for (int k = 0; k < 128; ++k) v += w3[j*128+k] * h2[c][k];
        h3[c][j] = gelu_exact(v);
    }
    __syncthreads();
    if (tid < 128) {
        int c = tid >> 4, j = tid & 15;
        float v = b4[j];
        for (int k = 0; k < 64; ++k) v += w4[j*64+k] * h3[c][k];
        ws[OFF_TABLE + c*16 + j] = v;
    }
}

// ---------------------------------------------------------------- tokens + layer-0 qkv (fused, 1 wave / 16 tokens)
// Lane (lo,kg) computes exactly its qkv A-frag slice: token t0+lo, dims kg*8..+7.
__global__ void __launch_bounds__(64)
tokens_qkv(const float* __restrict__ obs, const float* __restrict__ abs_emb,
    const float* __restrict__ rel_w, const float* __restrict__ rel_b,
    const float* __restrict__ ang_w, const float* __restrict__ ang_b,
    const float* __restrict__ nbr_w, const float* __restrict__ nbr_b,
    const float* __restrict__ ws, float* __restrict__ X,
    const __bf16* __restrict__ Wq, const float* __restrict__ qbias,
    __bf16* __restrict__ Qb, __bf16* __restrict__ Kb, __bf16* __restrict__ Vt)
{
    __shared__ float tab[128];
    __shared__ int apos[4];
    int l = threadIdx.x;
    int lo = l & 15, kg = l >> 4;
    tab[l] = ws[OFF_TABLE + l];
    tab[l + 64] = ws[OFF_TABLE + l + 64];
    if (l < 4) apos[l] = ((const int*)ws)[l];
    __syncthreads();

    int t0 = blockIdx.x * 16;
    int b = t0 / NC;
    int n = (t0 % NC) + lo;
    int ap = apos[b];
    const float* goal = obs + NC;
    const float* wall = obs + 2 * NC;
    int i = n / SZ, j = n % SZ;

    float val[8];
    if (kg < 2) {
        int c0 = ((n == ap) ? 4 : 0) | ((goal[n] > 0.5f) ? 2 : 0) | ((wall[n] > 0.5f) ? 1 : 0);
        #pragma unroll
        for (int c = 0; c < 8; ++c) val[c] = tab[c0*16 + kg*8 + c];
    } else if (kg == 2) {
        #pragma unroll
        for (int o = 0; o < 4; ++o) val[o] = abs_emb[n*4 + o];
        int ar = ap / SZ, ac = ap % SZ;
        const float scc = 2.0f / (SZ - 1);
        float dr = (float)(ar - i) * scc;
        float dc = (float)(ac - j) * scc;
        #pragma unroll
        for (int o = 0; o < 4; ++o)
            val[4 + o] = rel_b[o] + rel_w[o*2+0]*dr + rel_w[o*2+1]*dc;
    } else {
        int ar = ap / SZ, ac = ap % SZ;
        const float scc = 2.0f / (SZ - 1);
        float dr = (float)(ar - i) * scc;
        float dc = (float)(ac - j) * scc;
        float ang = atan2f(dc, dr);
        float sa = sinf(ang), ca = cosf(ang);
        #pragma unroll
        for (int o = 0; o < 4; ++o)
            val[o] = ang_b[o] + ang_w[o*2+0]*sa + ang_w[o*2+1]*ca;
        int nb[4];
        nb[0] = (i > 0)      ? n - SZ : n;
        nb[1] = (i < SZ - 1) ? n + SZ : n;
        nb[2] = (j > 0)      ? n - 1  : n;
        nb[3] = (j < SZ - 1) ? n + 1  : n;
        float navg[16];
        #pragma unroll
        for (int c = 0; c < 16; ++c) navg[c] = 0.f;
        #pragma unroll
        for (int q = 0; q < 4; ++q) {
            int m = nb[q];
            int cq = ((m == ap) ? 4 : 0) | ((goal[m] > 0.5f) ? 2 : 0) | ((wall[m] > 0.5f) ? 1 : 0);
            #pragma unroll
            for (int c = 0; c < 16; ++c) navg[c] += tab[cq*16 + c];
        }
        #pragma unroll
        for (int o = 0; o < 4; ++o) {
            float v = nbr_b[o];
            #pragma unroll
            for (int c = 0; c < 16; ++c) v += nbr_w[o*16 + c] * (navg[c] * 0.25f);
            val[4 + o] = v;
        }
    }
    // write f32 X (residual stream) and build A-frag in-register
    bf16x8 a;
    #pragma unroll
    for (int jj = 0; jj < 8; ++jj) {
        X[(size_t)(t0 + lo) * DD + kg * 8 + jj] = val[jj];
        a[jj] = (__bf16)val[jj];
    }
    const f32x4 zero = {0, 0, 0, 0};
    f32x4 acc[6];
    #pragma unroll
    for (int nn = 0; nn < 6; ++nn) {
        bf16x8 bf = *reinterpret_cast<const bf16x8*>(Wq + (size_t)(nn * 16 + lo) * DD + kg * 8);
        acc[nn] = __builtin_amdgcn_mfma_f32_16x16x32_bf16(a, bf, zero, 0, 0, 0);
    }
    #pragma unroll
    for (int nn = 0; nn < 6; ++nn) {
        int o = nn * 16 + lo;
        float bi = qbias[o];
        int part = o >> 5, oo = o & 31;
        int h = oo >> 3, dd = oo & 7;
        size_t bh = (size_t)(b * NH + h);
        #pragma unroll
        for (int r = 0; r < 4; ++r) {
            int t = t0 + kg * 4 + r;
            int tn = t % NC;
            float s = acc[nn][r] + bi;
            if (part == 0)
                Qb[(bh * NC + tn) * HD + dd] = (__bf16)(s * 0.35355339059327373f);
            else if (part == 1)
                Kb[(bh * NC + tn) * HD + dd] = (__bf16)s;
            else
                Vt[(bh * HD + dd) * NC + tn] = (__bf16)s;
        }
    }
}

// ---------------------------------------------------------------- attention via MFMA (unchanged)
__global__ void __launch_bounds__(256)
attn_mfma(const __bf16* __restrict__ Qb, const __bf16* __restrict__ Kb,
          const __bf16* __restrict__ Vt, float* __restrict__ Op,
          float* __restrict__ Rs)
{
    __shared__ __bf16 Pl[4][16 * 36];
    int tid = threadIdx.x;
    int w = tid >> 6, l = tid & 63, lo = l & 15, kg = l >> 4;
    int job = blockIdx.x * 4 + w;
    int bh  = job / (NQB * KSP);
    int rem = job % (NQB * KSP);
    int qb = rem >> 1, ks = rem & 1;

    const f32x4 zero = {0, 0, 0, 0};
    bf16x8 qfrag = {};
    if (kg == 0)
        qfrag = *reinterpret_cast<const bf16x8*>(Qb + ((size_t)bh * NC + qb * 16 + lo) * HD);
    f32x4 acc = zero;
    __bf16* pl = &Pl[w][0];

    for (int ch = 0; ch < (NC / KSP) / 32; ++ch) {
        int k0 = ks * (NC / KSP) + ch * 32;
        bf16x8 kf0 = {}, kf1 = {};
        if (kg == 0) {
            kf0 = *reinterpret_cast<const bf16x8*>(Kb + ((size_t)bh * NC + k0 + lo) * HD);
            kf1 = *reinterpret_cast<const bf16x8*>(Kb + ((size_t)bh * NC + k0 + 16 + lo) * HD);
        }
        f32x4 s0 = __builtin_amdgcn_mfma_f32_16x16x32_bf16(kf0, qfrag, zero, 0, 0, 0);
        f32x4 s1 = __builtin_amdgcn_mfma_f32_16x16x32_bf16(kf1, qfrag, zero, 0, 0, 0);
        bf16x4 p0, p1;
        #pragma unroll
        for (int r = 0; r < 4; ++r) p0[r] = (__bf16)__expf(s0[r]);
        #pragma unroll
        for (int r = 0; r < 4; ++r) p1[r] = (__bf16)__expf(s1[r]);
        *reinterpret_cast<bf16x4*>(pl + lo * 36 + kg * 4)      = p0;
        *reinterpret_cast<bf16x4*>(pl + lo * 36 + 16 + kg * 4) = p1;
        bf16x8 pa = *reinterpret_cast<const bf16x8*>(pl + lo * 36 + kg * 8);
        bf16x8 vf = {};
        if (lo < 8) {
            vf = *reinterpret_cast<const bf16x8*>(Vt + ((size_t)bh * HD + lo) * NC + k0 + kg * 8);
        } else if (lo == 8) {
            #pragma unroll
            for (int jj = 0; jj < 8; ++jj) vf[jj] = (__bf16)1.0f;
        }
        acc = __builtin_amdgcn_mfma_f32_16x16x32_bf16(pa, vf, acc, 0, 0, 0);
    }
    if (lo < 8) {
        #pragma unroll
        for (int r = 0; r < 4; ++r)
            Op[(size_t)job * 128 + (kg * 4 + r) * 8 + lo] = acc[r];
    } else if (lo == 8) {
        #pragma unroll
        for (int r = 0; r < 4; ++r)
            Rs[(size_t)job * 16 + kg * 4 + r] = acc[r];
    }
}

// ---------------------------------------------------------------- fused layer tail:
// proj+LN1 (wave 0) -> ff split across 4 waves -> LN2 -> {next-layer qkv | mean}
template<int LAST>
__global__ void __launch_bounds__(256)
fused_layer(float* __restrict__ Xf,
    const float* __restrict__ Op, const float* __restrict__ Rs,
    const __bf16* __restrict__ Wo, const float* __restrict__ obias,
    const float* __restrict__ g1, const float* __restrict__ bg1,
    const __bf16* __restrict__ w1b, const float* __restrict__ fb1,
    const __bf16* __restrict__ w2b, const float* __restrict__ fb2,
    const float* __restrict__ g2, const float* __restrict__ bg2,
    const __bf16* __restrict__ Wqn, const float* __restrict__ qbn,
    __bf16* __restrict__ Qb, __bf16* __restrict__ Kb, __bf16* __restrict__ Vt,
    float* __restrict__ out)
{
    __shared__ __align__(16) __bf16 Xl[16 * 40];
    __shared__ __align__(16) __bf16 Hl[4][2][648];
    __shared__ __align__(16) float accred[4][64][16];
    int tid = threadIdx.x;
    int w = tid >> 6, l = tid & 63, lo = l & 15, kg = l >> 4;
    int t0 = blockIdx.x * 16;
    int b = t0 / NC, qb = (t0 % NC) >> 4;
    const f32x4 zero = {0, 0, 0, 0};

    float xr0[4], xr1[4];   // x' (LN1 out), wave 0 only
    if (w == 0) {
        int jb = ((b * NH + kg) * NQB + qb) * KSP;
        float rs = Rs[jb * 16 + lo] + Rs[(jb + 1) * 16 + lo];
        float inv = 1.0f / rs;
        const float* p0 = Op + (size_t)jb * 128 + lo * 8;
        const float* p1 = Op + (size_t)(jb + 1) * 128 + lo * 8;
        bf16x8 a;
        #pragma unroll
        for (int jj = 0; jj < 8; ++jj) a[jj] = (__bf16)((p0[jj] + p1[jj]) * inv);
        bf16x8 bf0 = *reinterpret_cast<const bf16x8*>(Wo + (size_t)lo * DD + kg * 8);
        bf16x8 bf1 = *reinterpret_cast<const bf16x8*>(Wo + (size_t)(16 + lo) * DD + kg * 8);
        f32x4 acc0 = __builtin_amdgcn_mfma_f32_16x16x32_bf16(a, bf0, zero, 0, 0, 0);
        f32x4 acc1 = __builtin_amdgcn_mfma_f32_16x16x32_bf16(a, bf1, zero, 0, 0, 0);
        float bi0 = obias[lo], bi1 = obias[16 + lo];
        float gg0 = g1[lo], gg1 = g1[16 + lo];
        float bb0 = bg1[lo], bb1 = bg1[16 + lo];
        #pragma unroll
        for (int r = 0; r < 4; ++r) {
            int t = t0 + kg * 4 + r;
            float y0 = Xf[(size_t)t * DD + lo]      + acc0[r] + bi0;
            float y1 = Xf[(size_t)t * DD + 16 + lo] + acc1[r] + bi1;
            float s = y0 + y1;
            s += __shfl_xor(s, 1, 16); s += __shfl_xor(s, 2, 16);
            s += __shfl_xor(s, 4, 16); s += __shfl_xor(s, 8, 16);
            float mu = s * (1.0f / DD);
            float d0 = y0 - mu, d1 = y1 - mu;
            float v = d0 * d0 + d1 * d1;
            v += __shfl_xor(v, 1, 16); v += __shfl_xor(v, 2, 16);
            v += __shfl_xor(v, 4, 16); v += __shfl_xor(v, 8, 16);
            float linv = 1.0f / sqrtf(v * (1.0f / DD) + 1e-5f);
            xr0[r] = d0 * linv * gg0 + bb0;
            xr1[r] = d1 * linv * gg1 + bb1;
            Xl[(kg * 4 + r) * 40 + lo]      = (__bf16)xr0[r];
            Xl[(kg * 4 + r) * 40 + 16 + lo] = (__bf16)xr1[r];
        }
    }
    __syncthreads();

    // ff: each wave handles DFF/4 = 512 f-dims (8 iterations of 64)
    bf16x8 a1 = *reinterpret_cast<const bf16x8*>(&Xl[lo * 40 + kg * 8]);
    f32x4 accA0 = zero, accA1 = zero, accB0 = zero, accB1 = zero;
    for (int cc = w * 512; cc < w * 512 + 512; cc += 64) {
        int cA = cc, cB = cc + 32;
        bf16x8 b1A0 = *reinterpret_cast<const bf16x8*>(w1b + (size_t)(cA + lo) * DD + kg*8);
        bf16x8 b1A1 = *reinterpret_cast<const bf16x8*>(w1b + (size_t)(cA + 16 + lo) * DD + kg*8);
        bf16x8 b1B0 = *reinterpret_cast<const bf16x8*>(w1b + (size_t)(cB + lo) * DD + kg*8);
        bf16x8 b1B1 = *reinterpret_cast<const bf16x8*>(w1b + (size_t)(cB + 16 + lo) * DD + kg*8);
        f32x4 c1A0 = __builtin_amdgcn_mfma_f32_16x16x32_bf16(a1, b1A0, zero, 0, 0, 0);
        f32x4 c1A1 = __builtin_amdgcn_mfma_f32_16x16x32_bf16(a1, b1A1, zero, 0, 0, 0);
        f32x4 c1B0 = __builtin_amdgcn_mfma_f32_16x16x32_bf16(a1, b1B0, zero, 0, 0, 0);
        f32x4 c1B1 = __builtin_amdgcn_mfma_f32_16x16x32_bf16(a1, b1B1, zero, 0, 0, 0);
        float bA0 = fb1[cA + lo], bA1 = fb1[cA + 16 + lo];
        float bB0 = fb1[cB + lo], bB1 = fb1[cB + 16 + lo];
        #pragma unroll
        for (int r = 0; r < 4; ++r) {
            int tok = kg * 4 + r;
            Hl[w][0][tok*40 + lo]      = (__bf16)fmaxf(c1A0[r] + bA0, 0.f);
            Hl[w][0][tok*40 + 16 + lo] = (__bf16)fmaxf(c1A1[r] + bA1, 0.f);
            Hl[w][1][tok*40 + lo]      = (__bf16)fmaxf(c1B0[r] + bB0, 0.f);
            Hl[w][1][tok*40 + 16 + lo] = (__bf16)fmaxf(c1B1[r] + bB1, 0.f);
        }
        bf16x8 a2A = *reinterpret_cast<const bf16x8*>(&Hl[w][0][lo*40 + kg*8]);
        bf16x8 a2B = *reinterpret_cast<const bf16x8*>(&Hl[w][1][lo*40 + kg*8]);
        bf16x8 b2A0 = *reinterpret_cast<const bf16x8*>(w2b + (size_t)lo * DFF + cA + kg*8);
        bf16x8 b2A1 = *reinterpret_cast<const bf16x8*>(w2b + (size_t)(16 + lo) * DFF + cA + kg*8);
        bf16x8 b2B0 = *reinterpret_cast<const bf16x8*>(w2b + (size_t)lo * DFF + cB + kg*8);
        bf16x8 b2B1 = *reinterpret_cast<const bf16x8*>(w2b + (size_t)(16 + lo) * DFF + cB + kg*8);
        accA0 = __builtin_amdgcn_mfma_f32_16x16x32_bf16(a2A, b2A0, accA0, 0, 0, 0);
        accA1 = __builtin_amdgcn_mfma_f32_16x16x32_bf16(a2A, b2A1, accA1, 0, 0, 0);
        accB0 = __builtin_amdgcn_mfma_f32_16x16x32_bf16(a2B, b2B0, accB0, 0, 0, 0);
        accB1 = __builtin_amdgcn_mfma_f32_16x16x32_bf16(a2B, b2B1, accB1, 0, 0, 0);
    }
    *reinterpret_cast<f32x4*>(&accred[w][l][0])  = accA0;
    *reinterpret_cast<f32x4*>(&accred[w][l][4])  = accA1;
    *reinterpret_cast<f32x4*>(&accred[w][l][8])  = accB0;
    *reinterpret_cast<f32x4*>(&accred[w][l][12]) = accB1;
    __syncthreads();
    if (w != 0) return;

    // reduce the 4 wave-partials
    accA0 = zero; accA1 = zero; accB0 = zero; accB1 = zero;
    #pragma unroll
    for (int ww = 0; ww < 4; ++ww) {
        accA0 += *reinterpret_cast<const f32x4*>(&accred[ww][l][0]);
        accA1 += *reinterpret_cast<const f32x4*>(&accred[ww][l][4]);
        accB0 += *reinterpret_cast<const f32x4*>(&accred[ww][l][8]);
        accB1 += *reinterpret_cast<const f32x4*>(&accred[ww][l][12]);
    }

    float b2v0 = fb2[lo], b2v1 = fb2[16 + lo];
    float gg0 = g2[lo], gg1 = g2[16 + lo];
    float bb0 = bg2[lo], bb1 = bg2[16 + lo];
    float s0 = 0.f, s1 = 0.f;
    #pragma unroll
    for (int r = 0; r < 4; ++r) {
        int t = t0 + kg * 4 + r;
        float y0 = xr0[r] + accA0[r] + accB0[r] + b2v0;
        float y1 = xr1[r] + accA1[r] + accB1[r] + b2v1;
        float s = y0 + y1;
        s += __shfl_xor(s, 1, 16); s += __shfl_xor(s, 2, 16);
        s += __shfl_xor(s, 4, 16); s += __shfl_xor(s, 8, 16);
        float mu = s * (1.0f / DD);
        float d0 = y0 - mu, d1 = y1 - mu;
        float v = d0 * d0 + d1 * d1;
        v += __shfl_xor(v, 1, 16); v += __shfl_xor(v, 2, 16);
        v += __shfl_xor(v, 4, 16); v += __shfl_xor(v, 8, 16);
        float linv = 1.0f / sqrtf(v * (1.0f / DD) + 1e-5f);
        float o0 = d0 * linv * gg0 + bb0;
        float o1 = d1 * linv * gg1 + bb1;
        if (!LAST) {
            Xf[(size_t)t * DD + lo]      = o0;
            Xf[(size_t)t * DD + 16 + lo] = o1;
            Xl[(kg * 4 + r) * 40 + lo]      = (__bf16)o0;
            Xl[(kg * 4 + r) * 40 + 16 + lo] = (__bf16)o1;
        } else {
            s0 += o0;
            s1 += o1;
        }
    }

    if (!LAST) {
        // next-layer qkv from Xl (wave-private LDS, in-order DS pipe)
        bf16x8 a = *reinterpret_cast<const bf16x8*>(&Xl[lo * 40 + kg * 8]);
        f32x4 accq[6];
        #pragma unroll
        for (int nn = 0; nn < 6; ++nn) {
            bf16x8 bf = *reinterpret_cast<const bf16x8*>(Wqn + (size_t)(nn * 16 + lo) * DD + kg * 8);
            accq[nn] = __builtin_amdgcn_mfma_f32_16x16x32_bf16(a, bf, zero, 0, 0, 0);
        }
        #pragma unroll
        for (int nn = 0; nn < 6; ++nn) {
            int o = nn * 16 + lo;
            float bi = qbn[o];
            int part = o >> 5, oo = o & 31;
            int h = oo >> 3, dd = oo & 7;
            size_t bh = (size_t)(b * NH + h);
            #pragma unroll
            for (int r = 0; r < 4; ++r) {
                int t = t0 + kg * 4 + r;
                int tn = t % NC;
                float s = accq[nn][r] + bi;
                if (part == 0)
                    Qb[(bh * NC + tn) * HD + dd] = (__bf16)(s * 0.35355339059327373f);
                else if (part == 1)
                    Kb[(bh * NC + tn) * HD + dd] = (__bf16)s;
                else
                    Vt[(bh * HD + dd) * NC + tn] = (__bf16)s;
            }
        }
    } else {
        // mean over this block's 16 tokens -> atomic accumulate
        s0 += __shfl_xor(s0, 16); s0 += __shfl_xor(s0, 32);
        s1 += __shfl_xor(s1, 16); s1 += __shfl_xor(s1, 32);
        if (l < 16) {
            atomicAdd(out + b * DD + lo,      s0 * (1.0f / NC));
            atomicAdd(out + b * DD + 16 + lo, s1 * (1.0f / NC));
        }
    }
}

// ---------------------------------------------------------------- launch
extern "C" void kernel_launch(void* const* d_in, const int* in_sizes, int n_in,
                              void* d_out, int out_size, void* d_ws, size_t ws_size,
                              hipStream_t stream) {
    const float* obs       = (const float*)d_in[0];
    const float* mlp_w1    = (const float*)d_in[1];
    const float* mlp_b1    = (const float*)d_in[2];
    const float* mlp_w2    = (const float*)d_in[3];
    const float* mlp_b2    = (const float*)d_in[4];
    const float* mlp_w3    = (const float*)d_in[5];
    const float* mlp_b3    = (const float*)d_in[6];
    const float* mlp_w4    = (const float*)d_in[7];
    const float* mlp_b4    = (const float*)d_in[8];
    const float* abs_emb   = (const float*)d_in[9];
    const float* rel_w     = (const float*)d_in[10];
    const float* rel_b     = (const float*)d_in[11];
    const float* ang_w     = (const float*)d_in[12];
    const float* ang_b     = (const float*)d_in[13];
    const float* nbr_w     = (const float*)d_in[14];
    const float* nbr_b     = (const float*)d_in[15];
    const float* attn_in_w = (const float*)d_in[16];
    const float* attn_in_b = (const float*)d_in[17];
    const float* attn_out_w= (const float*)d_in[18];
    const float* attn_out_b= (const float*)d_in[19];
    const float* ff_w1     = (const float*)d_in[20];
    const float* ff_b1     = (const float*)d_in[21];
    const float* ff_w2     = (const float*)d_in[22];
    const float* ff_b2     = (const float*)d_in[23];
    const float* ln1_g     = (const float*)d_in[24];
    const float* ln1_b     = (const float*)d_in[25];
    const float* ln2_g     = (const float*)d_in[26];
    const float* ln2_b     = (const float*)d_in[27];

    float* ws = (float*)d_ws;
    float* X  = ws + OFF_X;
    __bf16* Qb = (__bf16*)(ws + OFF_QB);
    __bf16* Kb = (__bf16*)(ws + OFF_KB);
    __bf16* Vt = (__bf16*)(ws + OFF_VT);
    float* Op = ws + OFF_OP;
    float* Rs = ws + OFF_RS;
    __bf16* w1b = (__bf16*)(ws + OFF_W1B);
    __bf16* w2b = (__bf16*)(ws + OFF_W2B);
    __bf16* wqb = (__bf16*)(ws + OFF_WQB);
    __bf16* wob = (__bf16*)(ws + OFF_WOB);
    float* out = (float*)d_out;

    setup_convert<<<512, 256, 0, stream>>>(obs,
        mlp_w1, mlp_b1, mlp_w2, mlp_b2, mlp_w3, mlp_b3, mlp_w4, mlp_b4,
        ff_w1, ff_w2, attn_in_w, attn_out_w,
        ws, w1b, w2b, wqb, wob, out);
    tokens_qkv<<<(BB*NC)/16, 64, 0, stream>>>(obs, abs_emb, rel_w, rel_b,
        ang_w, ang_b, nbr_w, nbr_b, ws, X,
        wqb, attn_in_b, Qb, Kb, Vt);

    attn_mfma<<<JOBS/4, 256, 0, stream>>>(Qb, Kb, Vt, Op, Rs);
    fused_layer<0><<<(BB*NC)/16, 256, 0, stream>>>(
        X, Op, Rs,
        wob, attn_out_b, ln1_g, ln1_b,
        w1b, ff_b1, w2b, ff_b2, ln2_g, ln2_b,
        wqb + (size_t)96*DD, attn_in_b + 96, Qb, Kb, Vt, out);

    attn_mfma<<<JOBS/4, 256, 0, stream>>>(Qb, Kb, Vt, Op, Rs);
    fused_layer<1><<<(BB*NC)/16, 256, 0, stream>>>(
        X, Op, Rs,
        wob + (size_t)DD*DD, attn_out_b + DD, ln1_g + DD, ln1_b + DD,
        w1b + (size_t)DFF*DD, ff_b1 + DFF, w2b + (size_t)DD*DFF, ff_b2 + DD,
        ln2_g + DD, ln2_b + DD,
        nullptr, nullptr, nullptr, nullptr, nullptr, out);
}